// Round 1
// baseline (896.824 us; speedup 1.0000x reference)
//
#include <hip/hip_runtime.h>

#define L_HIST 2048

// ---------------- workspace layout (float offsets), total ~38.4 MB ----------
#define WS_WFLAT 0                          // W_tau = A^tau B, tau<32: (512 x 8192)
#define WS_UPACK (WS_WFLAT + 512*8192)      // (8192 x 64)
#define WS_P1    (WS_UPACK + 8192*64)       // [A^{32 j1}] j1<8 : (512 x 4096)
#define WS_P2    (WS_P1 + 512*4096)         // [A^{256 j2}] j2<8: (512 x 4096)
#define WS_POWA  (WS_P2 + 512*4096)         // ping (512x512)
#define WS_POWB  (WS_POWA + 512*512)        // pong (512x512)
#define WS_Q     (WS_POWB + 512*512)        // (512 x 64)
#define WS_QRE   (WS_Q + 512*64)            // (4096 x 8)
#define WS_R     (WS_QRE + 4096*8)          // (512 x 8)
#define WS_RFLAT (WS_R + 512*8)             // (4096)
#define WS_S     (WS_RFLAT + 4096)          // (512)
#define WS_QPRED (WS_S + 512)               // (512)
#define WS_WVEC  (WS_QPRED + 512)           // 306 weight vectors x 256

// ---------------- generic fp32 GEMM, 32x32 tile, optional split-K -----------
// C[M=512 x N] = A[512 x K] * B[K x N], row-major with leading dims.
// If gridDim.z > 1, accumulates with atomicAdd (caller must pre-zero C).
__global__ __launch_bounds__(256) void gemm32(
    const float* __restrict__ A, int lda,
    const float* __restrict__ B, int ldb,
    float* __restrict__ Cc, int ldc,
    int N, int K, int kchunk) {
  __shared__ float As[32][36];
  __shared__ float Bs[32][36];
  int tid = threadIdx.x;
  int col0 = blockIdx.x * 32;
  int row0 = blockIdx.y * 32;
  int kstart = blockIdx.z * kchunk;
  int kend = kstart + kchunk; if (kend > K) kend = K;
  int ty = tid >> 4, tx = tid & 15;
  float acc00 = 0.f, acc01 = 0.f, acc10 = 0.f, acc11 = 0.f;
  int lr = tid >> 3;        // 0..31
  int lk = (tid & 7) * 4;   // 0,4,...,28
  for (int kt = kstart; kt < kend; kt += 32) {
    {
      const float* src = A + (size_t)(row0 + lr) * lda + kt + lk;
      float4 v = *(const float4*)src;           // M=512 always in-bounds; K mult of 32
      As[lk + 0][lr] = v.x; As[lk + 1][lr] = v.y;
      As[lk + 2][lr] = v.z; As[lk + 3][lr] = v.w;
    }
    {
      int kk = tid >> 3;
      int c = (tid & 7) * 4;
      int gc = col0 + c;
      const float* src = B + (size_t)(kt + kk) * ldb + gc;
      float4 v;
      if (gc + 3 < N) v = *(const float4*)src;
      else {
        v.x = (gc + 0 < N) ? src[0] : 0.f; v.y = (gc + 1 < N) ? src[1] : 0.f;
        v.z = (gc + 2 < N) ? src[2] : 0.f; v.w = (gc + 3 < N) ? src[3] : 0.f;
      }
      *(float4*)&Bs[kk][c] = v;
    }
    __syncthreads();
#pragma unroll
    for (int k = 0; k < 32; ++k) {
      float2 av = *(const float2*)&As[k][ty * 2];
      float2 bv = *(const float2*)&Bs[k][tx * 2];
      acc00 += av.x * bv.x; acc01 += av.x * bv.y;
      acc10 += av.y * bv.x; acc11 += av.y * bv.y;
    }
    __syncthreads();
  }
  int r = row0 + ty * 2, c = col0 + tx * 2;
  bool split = (gridDim.z > 1);
  float vals[2][2] = {{acc00, acc01}, {acc10, acc11}};
  for (int i = 0; i < 2; ++i)
    for (int j = 0; j < 2; ++j) {
      int cc = c + j;
      if (cc < N) {
        float* dst = Cc + (size_t)(r + i) * ldc + cc;
        if (split) atomicAdd(dst, vals[i][j]);
        else *dst = vals[i][j];
      }
    }
}

// ---------------- fp32 GEMM, 64x64 tile (for big-N chain GEMMs) -------------
__global__ __launch_bounds__(256) void gemm64(
    const float* __restrict__ A, int lda,
    const float* __restrict__ B, int ldb,
    float* __restrict__ Cc, int ldc,
    int N, int K) {
  __shared__ float As[16][68];
  __shared__ float Bs[16][68];
  int tid = threadIdx.x;
  int col0 = blockIdx.x * 64;
  int row0 = blockIdx.y * 64;
  int ty = tid >> 4, tx = tid & 15;
  float acc[4][4] = {};
  int lr = tid >> 2;        // 0..63
  int lk = (tid & 3) * 4;   // 0,4,8,12
  for (int kt = 0; kt < K; kt += 16) {
    {
      const float* src = A + (size_t)(row0 + lr) * lda + kt + lk;
      float4 v = *(const float4*)src;
      As[lk + 0][lr] = v.x; As[lk + 1][lr] = v.y;
      As[lk + 2][lr] = v.z; As[lk + 3][lr] = v.w;
    }
    {
      int kk = tid >> 4;
      int c = (tid & 15) * 4;
      int gc = col0 + c;
      const float* src = B + (size_t)(kt + kk) * ldb + gc;
      float4 v;
      if (gc + 3 < N) v = *(const float4*)src;
      else {
        v.x = (gc + 0 < N) ? src[0] : 0.f; v.y = (gc + 1 < N) ? src[1] : 0.f;
        v.z = (gc + 2 < N) ? src[2] : 0.f; v.w = (gc + 3 < N) ? src[3] : 0.f;
      }
      *(float4*)&Bs[kk][c] = v;
    }
    __syncthreads();
#pragma unroll
    for (int k = 0; k < 16; ++k) {
      float4 av = *(const float4*)&As[k][ty * 4];
      float4 bv = *(const float4*)&Bs[k][tx * 4];
      float a_[4] = {av.x, av.y, av.z, av.w};
      float b_[4] = {bv.x, bv.y, bv.z, bv.w};
#pragma unroll
      for (int i = 0; i < 4; ++i)
#pragma unroll
        for (int j = 0; j < 4; ++j)
          acc[i][j] += a_[i] * b_[j];
    }
    __syncthreads();
  }
  for (int i = 0; i < 4; ++i) {
    int r = row0 + ty * 4 + i;
    for (int j = 0; j < 4; ++j) {
      int cc = col0 + tx * 4 + j;
      if (cc < N) Cc[(size_t)r * ldc + cc] = acc[i][j];
    }
  }
}

// ---------------- packing / init kernels ------------------------------------
// Upack[(tau*256+c)*64 + j] = u_rev[32 j + tau][c] = u_history[2047-32j-tau][c]
__global__ void pack_upack(const float* __restrict__ uh, float* __restrict__ up) {
  int idx = blockIdx.x * 256 + threadIdx.x;   // < 8192*64
  int j = idx & 63, row = idx >> 6;
  int tau = row >> 8, c = row & 255;
  up[idx] = uh[(size_t)(L_HIST - 1 - (32 * j + tau)) * 256 + c];
}

// Wflat[:, 0:256] = B
__global__ void copyB_kernel(const float* __restrict__ B, float* __restrict__ Wflat) {
  int idx = blockIdx.x * 256 + threadIdx.x;   // < 512*256
  int r = idx >> 8, c = idx & 255;
  Wflat[(size_t)r * 8192 + c] = B[idx];
}

// stack[:, 0:512] = I; stack[:, 512:1024] = pw
__global__ void init_stack(float* __restrict__ dst, const float* __restrict__ pw) {
  int idx = blockIdx.x * 256 + threadIdx.x;   // < 512*1024
  int r = idx >> 10, c = idx & 1023;
  dst[(size_t)r * 4096 + c] = (c < 512) ? ((r == c) ? 1.f : 0.f)
                                        : pw[(size_t)r * 512 + (c - 512)];
}

// Qre[(j1*512+m)*8 + j2] = Q[m][j1 + 8*j2]
__global__ void pack_qre(const float* __restrict__ Q, float* __restrict__ qre) {
  int idx = blockIdx.x * 256 + threadIdx.x;   // < 4096*8
  int j2 = idx & 7, row = idx >> 3;
  int j1 = row >> 9, m = row & 511;
  qre[idx] = Q[(size_t)m * 64 + j1 + 8 * j2];
}

// Rflat[j2*512+m] = R[m][j2]
__global__ void pack_rflat(const float* __restrict__ R, float* __restrict__ rf) {
  int idx = blockIdx.x * 256 + threadIdx.x;   // < 4096
  int j2 = idx >> 9, m = idx & 511;
  rf[idx] = R[(size_t)m * 8 + j2];
}

// qpred[r] = sum_{tau<16} (W_tau u_rev[tau])[r]
__global__ __launch_bounds__(64) void qpred_kernel(
    const float* __restrict__ Wflat, const float* __restrict__ uh,
    float* __restrict__ qpred) {
  int r = blockIdx.x;             // 0..511
  int lane = threadIdx.x;
  float acc = 0.f;
  for (int t = lane; t < 4096; t += 64) {
    int tau = t >> 8, c = t & 255;
    acc += Wflat[(size_t)r * 8192 + t] * uh[(size_t)(L_HIST - 1 - tau) * 256 + c];
  }
  for (int off = 32; off > 0; off >>= 1) acc += __shfl_down(acc, off);
  if (lane == 0) qpred[r] = acc;
}

// out[p] = y_hist[-1][p] - (C s)[p]; out[256+p] = out[p] + (C qpred)[p]
__global__ __launch_bounds__(64) void finalize_kernel(
    const float* __restrict__ Cmat, const float* __restrict__ svec,
    const float* __restrict__ qpred, const float* __restrict__ yh,
    float* __restrict__ out) {
  int p = blockIdx.x;             // 0..255
  int lane = threadIdx.x;
  float a1 = 0.f, a2 = 0.f;
  for (int t = lane; t < 512; t += 64) {
    float cv = Cmat[(size_t)p * 512 + t];
    a1 += cv * svec[t];
    a2 += cv * qpred[t];
  }
  for (int off = 32; off > 0; off >>= 1) {
    a1 += __shfl_down(a1, off);
    a2 += __shfl_down(a2, off);
  }
  if (lane == 0) {
    float ynat = yh[(size_t)(L_HIST - 1) * 256 + p] - a1;
    out[p] = ynat;
    out[256 + p] = ynat + a2;
  }
}

// ---------------- u_t: weight vectors for the 306 matvecs -------------------
// v=0: Yrev[0];  v=1..16 (i=v-1): lam4_i * sum_j pt[j,i] Yrev[1+j]
// v=17..33 (l=v-17): sig4_l * sum_k phi[k,l] Yrev[k]
// v>=34 (i,l): lam4_i sig4_l * sum_m W4[m] Yrev[2+m], W4[m]=sum_{j+k=m} pt[j,i] phi[k,l]
__global__ __launch_bounds__(256) void weights_kernel(
    const float* __restrict__ ynh, const float* __restrict__ sigma,
    const float* __restrict__ phi, const float* __restrict__ lambda_e,
    const float* __restrict__ phi_tilde, float* __restrict__ wvec,
    float* __restrict__ out) {
  int v = blockIdx.x;
  int p = threadIdx.x;
  __shared__ float w4[48];
  float val = 0.f;
  if (v == 0) {
    val = ynh[(size_t)(L_HIST - 1) * 256 + p];
    out[512 + p] = 0.f;   // zero the u_t accumulator region
  } else if (v <= 16) {
    int i = v - 1;
    float s = 0.f;
    for (int j = 0; j < 24; ++j)
      s += phi_tilde[j * 16 + i] * ynh[(size_t)(L_HIST - 2 - j) * 256 + p];
    val = powf(lambda_e[i], 0.25f) * s;
  } else if (v <= 33) {
    int l = v - 17;
    float s = 0.f;
    for (int k = 0; k < 25; ++k)
      s += phi[k * 17 + l] * ynh[(size_t)(L_HIST - 1 - k) * 256 + p];
    val = powf(sigma[l], 0.25f) * s;
  } else {
    int t = v - 34;
    int i = t / 17, l = t % 17;
    if (p < 48) {
      int m = p;
      int jlo = m - 24; if (jlo < 0) jlo = 0;
      int jhi = m; if (jhi > 23) jhi = 23;
      float s = 0.f;
      for (int j = jlo; j <= jhi; ++j)
        s += phi_tilde[j * 16 + i] * phi[(m - j) * 17 + l];
      w4[p] = s;
    }
    __syncthreads();
    float s = 0.f;
    for (int m = 0; m < 48; ++m)
      s += w4[m] * ynh[(size_t)(L_HIST - 3 - m) * 256 + p];
    val = powf(lambda_e[i], 0.25f) * powf(sigma[l], 0.25f) * s;
  }
  wvec[v * 256 + p] = val;
}

// ---------------- u_t: 306 matvecs streaming M / M_bar ----------------------
// grid = 306*4 blocks; block handles 64 rows of one matrix. atomicAdd into out.
__global__ __launch_bounds__(256) void ut_gemv(
    const float* __restrict__ Mtens, const float* __restrict__ Mbar,
    const float* __restrict__ wvec, float* __restrict__ out) {
  int v = blockIdx.x >> 2;
  int sub = blockIdx.x & 3;
  __shared__ float shw[256];
  shw[threadIdx.x] = wvec[v * 256 + threadIdx.x];
  __syncthreads();
  const float* mat;
  if (v == 0) mat = Mbar;
  else if (v <= 16) mat = Mbar + (size_t)v * 65536;
  else if (v <= 33) mat = Mtens + (size_t)(v - 17) * 65536;
  else {
    int t = v - 34;
    int i = t / 17, l = t % 17;
    mat = Mtens + (size_t)((1 + i) * 17 + l) * 65536;
  }
  int lane = threadIdx.x & 63;
  int wid = threadIdx.x >> 6;
  int nbase = sub * 64;
  for (int n = nbase + wid; n < nbase + 64; n += 4) {
    float4 mv = ((const float4*)(mat + (size_t)n * 256))[lane];
    float4 wv = *((const float4*)&shw[lane * 4]);
    float acc = mv.x * wv.x + mv.y * wv.y + mv.z * wv.z + mv.w * wv.w;
    for (int off = 32; off > 0; off >>= 1) acc += __shfl_down(acc, off);
    if (lane == 0) atomicAdd(&out[512 + n], acc);
  }
}

// ---------------- host orchestration ----------------------------------------
extern "C" void kernel_launch(void* const* d_in, const int* in_sizes, int n_in,
                              void* d_out, int out_size, void* d_ws, size_t ws_size,
                              hipStream_t stream) {
  (void)in_sizes; (void)n_in; (void)out_size; (void)ws_size;
  const float* A   = (const float*)d_in[0];
  const float* B   = (const float*)d_in[1];
  const float* C   = (const float*)d_in[2];
  const float* M   = (const float*)d_in[3];
  const float* Mb  = (const float*)d_in[4];
  const float* sig = (const float*)d_in[5];
  const float* phi = (const float*)d_in[6];
  const float* lam = (const float*)d_in[7];
  const float* pt  = (const float*)d_in[8];
  const float* yh  = (const float*)d_in[9];
  const float* uh  = (const float*)d_in[10];
  const float* ynh = (const float*)d_in[11];
  float* out = (float*)d_out;
  float* ws  = (float*)d_ws;

  float* Wflat = ws + WS_WFLAT;
  float* Upack = ws + WS_UPACK;
  float* P1    = ws + WS_P1;
  float* P2    = ws + WS_P2;
  float* powA  = ws + WS_POWA;
  float* powB  = ws + WS_POWB;
  float* Q     = ws + WS_Q;
  float* Qre   = ws + WS_QRE;
  float* R     = ws + WS_R;
  float* Rflat = ws + WS_RFLAT;
  float* svec  = ws + WS_S;
  float* qpred = ws + WS_QPRED;
  float* wvec  = ws + WS_WVEC;

  auto g32 = [&](const float* a, int lda, const float* b, int ldb,
                 float* c, int ldc, int N, int K, int z) {
    int kchunk = K / z;
    dim3 grid((N + 31) / 32, 16, z);
    gemm32<<<grid, 256, 0, stream>>>(a, lda, b, ldb, c, ldc, N, K, kchunk);
  };
  auto g64 = [&](const float* a, int lda, const float* b, int ldb,
                 float* c, int ldc, int N, int K) {
    dim3 grid((N + 63) / 64, 8);
    gemm64<<<grid, 256, 0, stream>>>(a, lda, b, ldb, c, ldc, N, K);
  };

  // ---- u_rev packing + W chain: W_tau = A^tau B, tau < 32 (doubling) ----
  pack_upack<<<2048, 256, 0, stream>>>(uh, Upack);
  copyB_kernel<<<512, 256, 0, stream>>>(B, Wflat);
  g32(A, 512, Wflat, 8192, Wflat + 256, 8192, 256, 512, 1);     // [AB]
  g32(A, 512, A, 512, powA, 512, 512, 512, 1);                  // A^2
  g32(powA, 512, Wflat, 8192, Wflat + 512, 8192, 512, 512, 1);  // [A2B,A3B]
  g32(powA, 512, powA, 512, powB, 512, 512, 512, 1);            // A^4
  g64(powB, 512, Wflat, 8192, Wflat + 1024, 8192, 1024, 512);   // tau 4..7
  g32(powB, 512, powB, 512, powA, 512, 512, 512, 1);            // A^8
  g64(powA, 512, Wflat, 8192, Wflat + 2048, 8192, 2048, 512);   // tau 8..15
  g32(powA, 512, powA, 512, powB, 512, 512, 512, 1);            // A^16
  g64(powB, 512, Wflat, 8192, Wflat + 4096, 8192, 4096, 512);   // tau 16..31

  // ---- power stacks P1 = [A^{32 j1}] j1<8, P2 = [A^{256 j2}] j2<8 ----
  g32(powB, 512, powB, 512, powA, 512, 512, 512, 1);            // A^32
  init_stack<<<2048, 256, 0, stream>>>(P1, powA);               // [I | A^32]
  g32(powA, 512, powA, 512, powB, 512, 512, 512, 1);            // A^64
  g64(powB, 512, P1, 4096, P1 + 1024, 4096, 1024, 512);         // [A^64,A^96]
  g32(powB, 512, powB, 512, powA, 512, 512, 512, 1);            // A^128
  g64(powA, 512, P1, 4096, P1 + 2048, 4096, 2048, 512);         // [A^128..A^224]
  g32(powA, 512, powA, 512, powB, 512, 512, 512, 1);            // A^256
  init_stack<<<2048, 256, 0, stream>>>(P2, powB);               // [I | A^256]
  g32(powB, 512, powB, 512, powA, 512, 512, 512, 1);            // A^512
  g64(powA, 512, P2, 4096, P2 + 1024, 4096, 1024, 512);         // [A^512,A^768]
  g32(powA, 512, powA, 512, powB, 512, 512, 512, 1);            // A^1024
  g64(powB, 512, P2, 4096, P2 + 2048, 4096, 2048, 512);         // [A^1024..A^1792]

  // ---- level reductions: Q (512x64), R (512x8), s (512) ----
  hipMemsetAsync(Q, 0, 512 * 64 * sizeof(float), stream);
  g32(Wflat, 8192, Upack, 64, Q, 64, 64, 8192, 8);              // split-K
  pack_qre<<<128, 256, 0, stream>>>(Q, Qre);
  hipMemsetAsync(R, 0, 512 * 8 * sizeof(float), stream);
  g32(P1, 4096, Qre, 8, R, 8, 8, 4096, 8);
  pack_rflat<<<16, 256, 0, stream>>>(R, Rflat);
  hipMemsetAsync(svec, 0, 512 * sizeof(float), stream);
  g32(P2, 4096, Rflat, 1, svec, 1, 1, 4096, 8);

  // ---- y_nat + pred ----
  qpred_kernel<<<512, 64, 0, stream>>>(Wflat, uh, qpred);
  finalize_kernel<<<256, 64, 0, stream>>>(C, svec, qpred, yh, out);

  // ---- u_t (weights, then 306 matvecs over M / M_bar) ----
  weights_kernel<<<306, 256, 0, stream>>>(ynh, sig, phi, lam, pt, wvec, out);
  ut_gemv<<<306 * 4, 256, 0, stream>>>(M, Mb, wvec, out);
}

// Round 2
// 580.034 us; speedup vs baseline: 1.5462x; 1.5462x over previous
//
#include <hip/hip_runtime.h>

#define L_HIST 2048

// ---------------- workspace layout (float offsets) --------------------------
// zeroed region (one big memset at launch start):
#define WS_WFLAT 0                          // W_tau = A^tau B, tau<32: 512 x 8192
#define WS_P1    (WS_WFLAT + 512*8192)      // [I,A^32,...,A^224]: 512 x 4096
#define WS_P2    (WS_P1 + 512*4096)         // [I,A^256,...,A^1792]: 512 x 4096
#define WS_POWS  (WS_P2 + 512*4096)         // two 512x512 scratch power slots
#define WS_Q     (WS_POWS + 2*512*512)      // 512 x 68 (col 64 = qpred)
#define WS_R     (WS_Q + 512*68)            // 512 x 8
#define WS_SV    (WS_R + 512*8)             // 512
#define WS_ZEND  (WS_SV + 512)              // ---- end of zeroed region ----
// not zeroed:
#define WS_UPACK WS_ZEND                    // 8192 x 68
#define WS_WVEC  (WS_UPACK + 8192*68)       // 306 x 256
// QRE / RFLAT alias the dead POWS region after the chain finishes:
#define WS_QRE   WS_POWS                    // 4096 x 8
#define WS_RF    (WS_POWS + 40960)          // 4096

// ---------------- dual-span fp32 GEMM, 64x64 tile, split-K ------------------
// C = A(512 x K) * [B1 (n1 cols) | B2], span1 -> C1, span2 -> C2.
// All span widths are multiples of 64. If gridDim.z>1, atomicAdd (dest pre-zeroed).
__global__ __launch_bounds__(256) void gemm64d(
    const float* __restrict__ Am, int lda,
    const float* __restrict__ B1, int ldb1, float* __restrict__ C1, int ldc1, int n1,
    const float* __restrict__ B2, int ldb2, float* __restrict__ C2, int ldc2,
    int K, int kchunk) {
  __shared__ float As[16][68];
  __shared__ float Bs[16][68];
  int tid = threadIdx.x;
  int c0 = blockIdx.x * 64;
  int row0 = blockIdx.y * 64;
  const float* B; float* Cc; int ldb, ldc, col;
  if (c0 < n1) { B = B1; ldb = ldb1; Cc = C1; ldc = ldc1; col = c0; }
  else         { B = B2; ldb = ldb2; Cc = C2; ldc = ldc2; col = c0 - n1; }
  int kstart = blockIdx.z * kchunk;
  int kend = kstart + kchunk; if (kend > K) kend = K;
  int ty = tid >> 4, tx = tid & 15;
  float acc[4][4] = {};
  int lr = tid >> 2;        // 0..63
  int lk = (tid & 3) * 4;   // 0,4,8,12
  for (int kt = kstart; kt < kend; kt += 16) {
    {
      const float* src = Am + (size_t)(row0 + lr) * lda + kt + lk;
      float4 v = *(const float4*)src;
      As[lk + 0][lr] = v.x; As[lk + 1][lr] = v.y;
      As[lk + 2][lr] = v.z; As[lk + 3][lr] = v.w;
    }
    {
      int kk = tid >> 4;
      int c = (tid & 15) * 4;
      const float* src = B + (size_t)(kt + kk) * ldb + col + c;
      *(float4*)&Bs[kk][c] = *(const float4*)src;
    }
    __syncthreads();
#pragma unroll
    for (int k = 0; k < 16; ++k) {
      float4 av = *(const float4*)&As[k][ty * 4];
      float4 bv = *(const float4*)&Bs[k][tx * 4];
      float a_[4] = {av.x, av.y, av.z, av.w};
      float b_[4] = {bv.x, bv.y, bv.z, bv.w};
#pragma unroll
      for (int i = 0; i < 4; ++i)
#pragma unroll
        for (int j = 0; j < 4; ++j)
          acc[i][j] += a_[i] * b_[j];
    }
    __syncthreads();
  }
  bool split = (gridDim.z > 1);
#pragma unroll
  for (int i = 0; i < 4; ++i) {
    int r = row0 + ty * 4 + i;
    float* dst = Cc + (size_t)r * ldc + col + tx * 4;
    if (split) {
#pragma unroll
      for (int j = 0; j < 4; ++j) atomicAdd(dst + j, acc[i][j]);
    } else {
      float4 v = {acc[i][0], acc[i][1], acc[i][2], acc[i][3]};
      *(float4*)dst = v;
    }
  }
}

// ---------------- fp32 GEMM, 32x32 tile, split-K, N-guarded (small N) -------
__global__ __launch_bounds__(256) void gemm32(
    const float* __restrict__ Am, int lda,
    const float* __restrict__ B, int ldb,
    float* __restrict__ Cc, int ldc,
    int N, int K, int kchunk) {
  __shared__ float As[32][36];
  __shared__ float Bs[32][36];
  int tid = threadIdx.x;
  int col0 = blockIdx.x * 32;
  int row0 = blockIdx.y * 32;
  int kstart = blockIdx.z * kchunk;
  int kend = kstart + kchunk; if (kend > K) kend = K;
  int ty = tid >> 4, tx = tid & 15;
  float acc00 = 0.f, acc01 = 0.f, acc10 = 0.f, acc11 = 0.f;
  int lr = tid >> 3;        // 0..31
  int lk = (tid & 7) * 4;   // 0..28
  for (int kt = kstart; kt < kend; kt += 32) {
    {
      const float* src = Am + (size_t)(row0 + lr) * lda + kt + lk;
      float4 v = *(const float4*)src;
      As[lk + 0][lr] = v.x; As[lk + 1][lr] = v.y;
      As[lk + 2][lr] = v.z; As[lk + 3][lr] = v.w;
    }
    {
      int kk = tid >> 3;
      int c = (tid & 7) * 4;
      int gc = col0 + c;
      const float* src = B + (size_t)(kt + kk) * ldb + gc;
      float4 v;
      if (gc + 3 < N) v = *(const float4*)src;
      else {
        v.x = (gc + 0 < N) ? src[0] : 0.f; v.y = (gc + 1 < N) ? src[1] : 0.f;
        v.z = (gc + 2 < N) ? src[2] : 0.f; v.w = (gc + 3 < N) ? src[3] : 0.f;
      }
      *(float4*)&Bs[kk][c] = v;
    }
    __syncthreads();
#pragma unroll
    for (int k = 0; k < 32; ++k) {
      float2 av = *(const float2*)&As[k][ty * 2];
      float2 bv = *(const float2*)&Bs[k][tx * 2];
      acc00 += av.x * bv.x; acc01 += av.x * bv.y;
      acc10 += av.y * bv.x; acc11 += av.y * bv.y;
    }
    __syncthreads();
  }
  int r = row0 + ty * 2, c = col0 + tx * 2;
  bool split = (gridDim.z > 1);
  float vals[2][2] = {{acc00, acc01}, {acc10, acc11}};
  for (int i = 0; i < 2; ++i)
    for (int j = 0; j < 2; ++j) {
      int cc = c + j;
      if (cc < N) {
        float* dst = Cc + (size_t)(r + i) * ldc + cc;
        if (split) atomicAdd(dst, vals[i][j]);
        else *dst = vals[i][j];
      }
    }
}

// ---------------- packing / init kernels ------------------------------------
// Upack[(tau*256+c)*68 + j]:
//   j<64 : u_rev[32j+tau][c];  j==64: tau<16 ? u_rev[tau][c] : 0;  j>64: 0
__global__ __launch_bounds__(256) void pack_upack(const float* __restrict__ uh,
                                                  float* __restrict__ up) {
  unsigned idx = blockIdx.x * 256 + threadIdx.x;   // < 8192*68
  unsigned r = idx / 68u, j = idx - r * 68u;
  unsigned tau = r >> 8, c = r & 255;
  float v = 0.f;
  if (j < 64) v = uh[(size_t)(L_HIST - 1 - (32 * j + tau)) * 256 + c];
  else if (j == 64 && tau < 16) v = uh[(size_t)(L_HIST - 1 - tau) * 256 + c];
  up[idx] = v;
}

__global__ __launch_bounds__(256) void copyB_kernel(const float* __restrict__ B,
                                                    float* __restrict__ Wflat) {
  int idx = blockIdx.x * 256 + threadIdx.x;   // < 512*256
  int r = idx >> 8, c = idx & 255;
  Wflat[(size_t)r * 8192 + c] = B[idx];
}

// write identity diagonals into (pre-zeroed) P1[:,0:512] and P2[:,0:512]
__global__ void init_identity(float* __restrict__ P1, float* __restrict__ P2) {
  int r = blockIdx.x * 256 + threadIdx.x;
  if (r < 512) { P1[(size_t)r * 4096 + r] = 1.f; P2[(size_t)r * 4096 + r] = 1.f; }
}

// Qre[(j1*512+m)*8 + j2] = Q[m][j1 + 8*j2]   (Q ld 68)
__global__ __launch_bounds__(256) void pack_qre(const float* __restrict__ Q,
                                                float* __restrict__ qre) {
  int idx = blockIdx.x * 256 + threadIdx.x;   // < 4096*8
  int j2 = idx & 7, row = idx >> 3;
  int j1 = row >> 9, m = row & 511;
  qre[idx] = Q[(size_t)m * 68 + j1 + 8 * j2];
}

// Rflat[j2*512+m] = R[m][j2]
__global__ __launch_bounds__(256) void pack_rflat(const float* __restrict__ R,
                                                  float* __restrict__ rf) {
  int idx = blockIdx.x * 256 + threadIdx.x;   // < 4096
  int j2 = idx >> 9, m = idx & 511;
  rf[idx] = R[(size_t)m * 8 + j2];
}

// out[p] = yh[-1][p] - (C s)[p]; out[256+p] = out[p] + (C qpred)[p], qpred=Q[:,64]
__global__ __launch_bounds__(64) void finalize_kernel(
    const float* __restrict__ Cmat, const float* __restrict__ svec,
    const float* __restrict__ Q, const float* __restrict__ yh,
    float* __restrict__ out) {
  int p = blockIdx.x;             // 0..255
  int lane = threadIdx.x;
  float a1 = 0.f, a2 = 0.f;
  for (int t = lane; t < 512; t += 64) {
    float cv = Cmat[(size_t)p * 512 + t];
    a1 += cv * svec[t];
    a2 += cv * Q[(size_t)t * 68 + 64];
  }
  for (int off = 32; off > 0; off >>= 1) {
    a1 += __shfl_down(a1, off);
    a2 += __shfl_down(a2, off);
  }
  if (lane == 0) {
    float ynat = yh[(size_t)(L_HIST - 1) * 256 + p] - a1;
    out[p] = ynat;
    out[256 + p] = ynat + a2;
  }
}

// ---------------- u_t: weight vectors for the 306 matvecs -------------------
__global__ __launch_bounds__(256) void weights_kernel(
    const float* __restrict__ ynh, const float* __restrict__ sigma,
    const float* __restrict__ phi, const float* __restrict__ lambda_e,
    const float* __restrict__ phi_tilde, float* __restrict__ wvec,
    float* __restrict__ out) {
  int v = blockIdx.x;
  int p = threadIdx.x;
  __shared__ float w4[48];
  float val = 0.f;
  if (v == 0) {
    val = ynh[(size_t)(L_HIST - 1) * 256 + p];
    out[512 + p] = 0.f;   // zero the u_t accumulator region
  } else if (v <= 16) {
    int i = v - 1;
    float s = 0.f;
    for (int j = 0; j < 24; ++j)
      s += phi_tilde[j * 16 + i] * ynh[(size_t)(L_HIST - 2 - j) * 256 + p];
    val = powf(lambda_e[i], 0.25f) * s;
  } else if (v <= 33) {
    int l = v - 17;
    float s = 0.f;
    for (int k = 0; k < 25; ++k)
      s += phi[k * 17 + l] * ynh[(size_t)(L_HIST - 1 - k) * 256 + p];
    val = powf(sigma[l], 0.25f) * s;
  } else {
    int t = v - 34;
    int i = t / 17, l = t % 17;
    if (p < 48) {
      int m = p;
      int jlo = m - 24; if (jlo < 0) jlo = 0;
      int jhi = m; if (jhi > 23) jhi = 23;
      float s = 0.f;
      for (int j = jlo; j <= jhi; ++j)
        s += phi_tilde[j * 16 + i] * phi[(m - j) * 17 + l];
      w4[p] = s;
    }
    __syncthreads();
    float s = 0.f;
    for (int m = 0; m < 48; ++m)
      s += w4[m] * ynh[(size_t)(L_HIST - 3 - m) * 256 + p];
    val = powf(lambda_e[i], 0.25f) * powf(sigma[l], 0.25f) * s;
  }
  wvec[v * 256 + p] = val;
}

// ---------------- u_t: streaming per-lane accumulation ----------------------
// out[512+n] = sum_v M_v[n,:] . w_v.  Block = (n, half); wave wid strides v by 4.
// Per-lane float4 accumulate -> one reduce+atomic per wave. mat for v>=17 is
// Mtens + (v-17)*65536 (verified: v=34+17i+l -> (1+i)*17+l), v<17: Mbar+v*65536.
__global__ __launch_bounds__(256) void ut_gemv(
    const float* __restrict__ Mtens, const float* __restrict__ Mbar,
    const float* __restrict__ wvec, float* __restrict__ out) {
  int n = blockIdx.x >> 1;
  int h = blockIdx.x & 1;
  int lane = threadIdx.x & 63;
  int wid = threadIdx.x >> 6;
  int vend = h * 153 + 153;
  float4 acc = {0.f, 0.f, 0.f, 0.f};
#pragma unroll 4
  for (int v = h * 153 + wid; v < vend; v += 4) {
    const float* mat = (v < 17 ? Mbar : Mtens - 17 * 65536) + (size_t)v * 65536;
    float4 mv = ((const float4*)(mat + (size_t)n * 256))[lane];
    float4 wv = ((const float4*)(wvec + (size_t)v * 256))[lane];
    acc.x += mv.x * wv.x; acc.y += mv.y * wv.y;
    acc.z += mv.z * wv.z; acc.w += mv.w * wv.w;
  }
  float a = (acc.x + acc.y) + (acc.z + acc.w);
  for (int off = 32; off > 0; off >>= 1) a += __shfl_down(a, off);
  if (lane == 0) atomicAdd(&out[512 + n], a);
}

// ---------------- host orchestration ----------------------------------------
extern "C" void kernel_launch(void* const* d_in, const int* in_sizes, int n_in,
                              void* d_out, int out_size, void* d_ws, size_t ws_size,
                              hipStream_t stream) {
  (void)in_sizes; (void)n_in; (void)out_size; (void)ws_size;
  const float* A   = (const float*)d_in[0];
  const float* B   = (const float*)d_in[1];
  const float* C   = (const float*)d_in[2];
  const float* M   = (const float*)d_in[3];
  const float* Mb  = (const float*)d_in[4];
  const float* sig = (const float*)d_in[5];
  const float* phi = (const float*)d_in[6];
  const float* lam = (const float*)d_in[7];
  const float* pt  = (const float*)d_in[8];
  const float* yh  = (const float*)d_in[9];
  const float* uh  = (const float*)d_in[10];
  const float* ynh = (const float*)d_in[11];
  float* out = (float*)d_out;
  float* ws  = (float*)d_ws;

  float* Wf    = ws + WS_WFLAT;
  float* P1    = ws + WS_P1;
  float* P2    = ws + WS_P2;
  float* s0    = ws + WS_POWS;
  float* s1    = s0 + 512 * 512;
  float* Q     = ws + WS_Q;
  float* R     = ws + WS_R;
  float* SV    = ws + WS_SV;
  float* Upack = ws + WS_UPACK;
  float* wvec  = ws + WS_WVEC;
  float* Qre   = ws + WS_QRE;
  float* Rf    = ws + WS_RF;

  auto g64d = [&](const float* a, int lda,
                  const float* b1, int ldb1, float* c1, int ldc1, int n1,
                  const float* b2, int ldb2, float* c2, int ldc2, int n2,
                  int K, int z) {
    dim3 grid((n1 + n2) / 64, 8, z);
    gemm64d<<<grid, 256, 0, stream>>>(a, lda, b1, ldb1, c1, ldc1, n1,
                                      b2, ldb2, c2, ldc2, K, K / z);
  };
  auto g32 = [&](const float* a, int lda, const float* b, int ldb,
                 float* c, int ldc, int N, int K, int z) {
    dim3 grid((N + 31) / 32, 16, z);
    gemm32<<<grid, 256, 0, stream>>>(a, lda, b, ldb, c, ldc, N, K, K / z);
  };

  // zero all atomic-accumulation destinations in one shot (~36 MB)
  hipMemsetAsync(ws, 0, (size_t)WS_ZEND * sizeof(float), stream);
  pack_upack<<<(8192 * 68) / 256, 256, 0, stream>>>(uh, Upack);
  copyB_kernel<<<512, 256, 0, stream>>>(B, Wf);
  init_identity<<<2, 256, 0, stream>>>(P1, P2);

  // ---- fused doubling chain: P_k · [P_k | W-block] (11 sequential GEMMs) ----
  g64d(A, 512,   A, 512, s0, 512, 512,    Wf, 8192, Wf + 256, 8192, 256,  512, 4);  // A2 | W1
  g64d(s0, 512,  s0, 512, s1, 512, 512,   Wf, 8192, Wf + 512, 8192, 512,  512, 2);  // A4 | W2:4
  hipMemsetAsync(s0, 0, 512 * 512 * sizeof(float), stream);
  g64d(s1, 512,  s1, 512, s0, 512, 512,   Wf, 8192, Wf + 1024, 8192, 1024, 512, 2); // A8 | W4:8
  g64d(s0, 512,  s0, 512, s1, 512, 512,   Wf, 8192, Wf + 2048, 8192, 2048, 512, 1); // A16| W8:16
  g64d(s1, 512,  s1, 512, P1 + 512, 4096, 512, Wf, 8192, Wf + 4096, 8192, 4096, 512, 1); // A32|W16:32
  g64d(P1 + 512, 4096,  P1 + 512, 4096, P1 + 1024, 4096, 512,
       nullptr, 0, nullptr, 0, 0, 512, 4);                                          // A64
  g64d(P1 + 1024, 4096, P1 + 512, 4096, P1 + 1536, 4096, 1024,
       nullptr, 0, nullptr, 0, 0, 512, 2);                                          // A96,A128
  g64d(P1 + 2048, 4096, P1 + 512, 4096, P1 + 2560, 4096, 1536,
       P1 + 2048, 4096, P2 + 512, 4096, 512, 512, 1);                               // A160..224 | A256
  g64d(P2 + 512, 4096,  P2 + 512, 4096, P2 + 1024, 4096, 512,
       nullptr, 0, nullptr, 0, 0, 512, 4);                                          // A512
  g64d(P2 + 1024, 4096, P2 + 512, 4096, P2 + 1536, 4096, 1024,
       nullptr, 0, nullptr, 0, 0, 512, 2);                                          // A768,A1024
  g64d(P2 + 2048, 4096, P2 + 512, 4096, P2 + 2560, 4096, 1536,
       nullptr, 0, nullptr, 0, 0, 512, 2);                                          // A1280..1792

  // ---- level reductions: Q (with qpred col), R, s ----
  g32(Wf, 8192, Upack, 68, Q, 68, 65, 8192, 8);
  pack_qre<<<128, 256, 0, stream>>>(Q, Qre);
  g32(P1, 4096, Qre, 8, R, 8, 8, 4096, 8);
  pack_rflat<<<16, 256, 0, stream>>>(R, Rf);
  g32(P2, 4096, Rf, 1, SV, 1, 1, 4096, 8);

  // ---- outputs ----
  finalize_kernel<<<256, 64, 0, stream>>>(C, SV, Q, yh, out);
  weights_kernel<<<306, 256, 0, stream>>>(ynh, sig, phi, lam, pt, wvec, out);
  ut_gemv<<<512, 256, 0, stream>>>(M, Mb, wvec, out);
}

// Round 3
// 566.825 us; speedup vs baseline: 1.5822x; 1.0233x over previous
//
#include <hip/hip_runtime.h>

#define L_HIST 2048
typedef unsigned short ushortT;
typedef __attribute__((ext_vector_type(8))) short bf16x8;
typedef __attribute__((ext_vector_type(4))) short bf16x4;
typedef __attribute__((ext_vector_type(16))) float f32x16;

__device__ __forceinline__ ushortT f2bf(float x) {
  union { float f; unsigned u; } v; v.f = x;
  unsigned r = (v.u + 0x7FFFu + ((v.u >> 16) & 1u)) >> 16;
  return (ushortT)r;
}
__device__ __forceinline__ float bf2f(ushortT h) {
  union { unsigned u; float f; } v; v.u = ((unsigned)h) << 16; return v.f;
}

// ---------------- job-table split-bf16 bt-GEMM ------------------------------
// D[m][n] = sum_k (Ph+Pl)[m][k] * (Qh+Ql)[n][k]   (3-product split emulation)
// K = 512 fixed, N = 512 fixed, M = jobs' M (mult of 128). ld = 512 everywhere.
// Output: bf16 planes Ch/Cl.
struct Job {
  const ushortT *Ph, *Pl, *Qh, *Ql;
  ushortT *Ch, *Cl;
  int M, tbase;
};
struct Prm { Job j[3]; int nj; };

__global__ __launch_bounds__(256) void bgemm(Prm p) {
  int bx = blockIdx.x;
  int ji = 0;
  if (p.nj > 1 && bx >= p.j[1].tbase) ji = 1;
  if (p.nj > 2 && bx >= p.j[2].tbase) ji = 2;
  Job J = p.j[ji];
  int lt = bx - J.tbase;
  int mt = J.M >> 7;
  int mtile = lt % mt, ntile = lt / mt;
  size_t m0 = (size_t)mtile * 128, n0 = (size_t)ntile * 128;

  __shared__ ushortT As[2][128][36];   // [plane][row][k], stride 36 (2-way-free)
  __shared__ ushortT Bs[2][128][36];

  int tid = threadIdx.x;
  int lane = tid & 63, wave = tid >> 6;
  int wm = (wave & 1) * 64, wn = (wave >> 1) * 64;
  int fr = lane & 31;
  int fk = (lane >> 5) * 8;
  int kpos = tid & 3;          // 16B chunk in 32-k tile
  int rowid = tid >> 2;        // 0..63

  f32x16 acc[2][2];
#pragma unroll
  for (int p_ = 0; p_ < 2; ++p_)
#pragma unroll
    for (int q_ = 0; q_ < 2; ++q_)
#pragma unroll
      for (int i = 0; i < 16; ++i) acc[p_][q_][i] = 0.f;

  for (int kt = 0; kt < 512; kt += 32) {
#pragma unroll
    for (int seg = 0; seg < 4; ++seg) {
      int row = rowid + ((seg & 1) << 6);
      int pl = seg >> 1;
      const ushortT* srcA = (pl ? J.Pl : J.Ph) + (m0 + row) * 512 + kt + kpos * 8;
      const ushortT* srcB = (pl ? J.Ql : J.Qh) + (n0 + row) * 512 + kt + kpos * 8;
      bf16x8 av = *(const bf16x8*)srcA;
      bf16x8 bv = *(const bf16x8*)srcB;
      *(bf16x4*)&As[pl][row][kpos * 8]     = __builtin_shufflevector(av, av, 0, 1, 2, 3);
      *(bf16x4*)&As[pl][row][kpos * 8 + 4] = __builtin_shufflevector(av, av, 4, 5, 6, 7);
      *(bf16x4*)&Bs[pl][row][kpos * 8]     = __builtin_shufflevector(bv, bv, 0, 1, 2, 3);
      *(bf16x4*)&Bs[pl][row][kpos * 8 + 4] = __builtin_shufflevector(bv, bv, 4, 5, 6, 7);
    }
    __syncthreads();
#pragma unroll
    for (int ks = 0; ks < 32; ks += 16) {
      bf16x8 af[2][2], bf_[2][2];
#pragma unroll
      for (int p_ = 0; p_ < 2; ++p_)
#pragma unroll
        for (int pl = 0; pl < 2; ++pl) {
          const ushortT* pa = &As[pl][wm + p_ * 32 + fr][ks + fk];
          bf16x4 alo = *(const bf16x4*)pa;
          bf16x4 ahi = *(const bf16x4*)(pa + 4);
          af[p_][pl] = __builtin_shufflevector(alo, ahi, 0, 1, 2, 3, 4, 5, 6, 7);
          const ushortT* pb = &Bs[pl][wn + p_ * 32 + fr][ks + fk];
          bf16x4 blo = *(const bf16x4*)pb;
          bf16x4 bhi = *(const bf16x4*)(pb + 4);
          bf_[p_][pl] = __builtin_shufflevector(blo, bhi, 0, 1, 2, 3, 4, 5, 6, 7);
        }
#pragma unroll
      for (int p_ = 0; p_ < 2; ++p_)
#pragma unroll
        for (int q_ = 0; q_ < 2; ++q_) {
          acc[p_][q_] = __builtin_amdgcn_mfma_f32_32x32x16_bf16(af[p_][0], bf_[q_][0], acc[p_][q_], 0, 0, 0);
          acc[p_][q_] = __builtin_amdgcn_mfma_f32_32x32x16_bf16(af[p_][0], bf_[q_][1], acc[p_][q_], 0, 0, 0);
          acc[p_][q_] = __builtin_amdgcn_mfma_f32_32x32x16_bf16(af[p_][1], bf_[q_][0], acc[p_][q_], 0, 0, 0);
        }
    }
    __syncthreads();
  }
  // epilogue: C/D layout col=lane&31, row=(reg&3)+8*(reg>>2)+4*(lane>>5)
#pragma unroll
  for (int p_ = 0; p_ < 2; ++p_)
#pragma unroll
    for (int q_ = 0; q_ < 2; ++q_)
#pragma unroll
      for (int i = 0; i < 16; ++i) {
        int row = wm + p_ * 32 + (i & 3) + ((i >> 2) << 3) + ((lane >> 5) << 2);
        int col = wn + q_ * 32 + (lane & 31);
        float v = acc[p_][q_][i];
        ushortT h = f2bf(v);
        float rem = v - bf2f(h);
        size_t off = (m0 + row) * 512 + (n0 + col);
        J.Ch[off] = h;
        J.Cl[off] = f2bf(rem);
      }
}

// ---------------- init / split kernels --------------------------------------
__global__ void split_A(const float* __restrict__ A, ushortT* N1h, ushortT* N1l,
                        ushortT* T1h, ushortT* T1l) {
  int idx = blockIdx.x * 256 + threadIdx.x;   // < 512*512
  int r = idx >> 9, c = idx & 511;
  float x = A[idx];
  ushortT h = f2bf(x); float rem = x - bf2f(h); ushortT l = f2bf(rem);
  N1h[idx] = h; N1l[idx] = l;
  T1h[c * 512 + r] = h; T1l[c * 512 + r] = l;
}

__global__ void split_B(const float* __restrict__ B, ushortT* WTh, ushortT* WTl) {
  int idx = blockIdx.x * 256 + threadIdx.x;   // < 512*256
  int d = idx >> 8, c = idx & 255;
  float x = B[idx];
  ushortT h = f2bf(x); float rem = x - bf2f(h);
  WTh[c * 512 + d] = h; WTl[c * 512 + d] = f2bf(rem);
}

// UT[j][k] (68 x 8192 fp32): j<64: u_rev[32j+tau][c]; j==64: tau<16 ? u_rev[tau][c] : 0
__global__ void pack_ut(const float* __restrict__ uh, float* __restrict__ UT) {
  int idx = blockIdx.x * 256 + threadIdx.x;   // < 68*8192
  int j = idx >> 13, k = idx & 8191;
  int tau = k >> 8, c = k & 255;
  float v = 0.f;
  if (j < 64) v = uh[(size_t)(L_HIST - 1 - (32 * j + tau)) * 256 + c];
  else if (j == 64 && tau < 16) v = uh[(size_t)(L_HIST - 1 - tau) * 256 + c];
  UT[idx] = v;
}

// ---------------- Q = W * Upack (fp32, reads WT planes coalesced) -----------
// Q[m][j] = sum_k (WTh+WTl)[k][m] * UT[j][k];  grid (32 kchunks, 4 jgroups), 512 thr
__global__ __launch_bounds__(512) void qgemv(const ushortT* __restrict__ WTh,
                                             const ushortT* __restrict__ WTl,
                                             const float* __restrict__ UT,
                                             float* __restrict__ Qb) {
  int m = threadIdx.x;
  int jg = blockIdx.y;
  int k0 = blockIdx.x * 256;
  float acc[17];
#pragma unroll
  for (int jj = 0; jj < 17; ++jj) acc[jj] = 0.f;
  for (int k = k0; k < k0 + 256; ++k) {
    size_t off = (size_t)k * 512 + m;
    float wv = bf2f(WTh[off]) + bf2f(WTl[off]);
#pragma unroll
    for (int jj = 0; jj < 17; ++jj)
      acc[jj] += wv * UT[(size_t)(jg * 17 + jj) * 8192 + k];
  }
#pragma unroll
  for (int jj = 0; jj < 17; ++jj)
    atomicAdd(&Qb[m * 68 + jg * 17 + jj], acc[jj]);
}

// ---------------- R[m][j2] = sum_{j1,d} A^{32j1}[m][d] Q[d][j1+8j2] ----------
__global__ __launch_bounds__(512) void rgemv(const ushortT* __restrict__ P1th,
                                             const ushortT* __restrict__ P1tl,
                                             const float* __restrict__ Qb,
                                             float* __restrict__ Rb) {
  int m = threadIdx.x;
  int j1 = blockIdx.x;   // 0..7
  int dc = blockIdx.y;   // 0..3
  if (j1 == 0) {
    if (dc == 0) {
#pragma unroll
      for (int j2 = 0; j2 < 8; ++j2)
        atomicAdd(&Rb[m * 8 + j2], Qb[m * 68 + 8 * j2]);
    }
    return;
  }
  float acc[8];
#pragma unroll
  for (int j2 = 0; j2 < 8; ++j2) acc[j2] = 0.f;
  int d0 = dc * 128;
  for (int d = d0; d < d0 + 128; ++d) {
    size_t off = ((size_t)(j1 - 1) * 512 + d) * 512 + m;
    float tv = bf2f(P1th[off]) + bf2f(P1tl[off]);
#pragma unroll
    for (int j2 = 0; j2 < 8; ++j2)
      acc[j2] += tv * Qb[d * 68 + j1 + 8 * j2];
  }
#pragma unroll
  for (int j2 = 0; j2 < 8; ++j2) atomicAdd(&Rb[m * 8 + j2], acc[j2]);
}

// ---------------- S[m] = sum_{j2,d} A^{256j2}[m][d] R[d][j2] ----------------
__global__ __launch_bounds__(512) void sgemv(const ushortT* __restrict__ P2th,
                                             const ushortT* __restrict__ P2tl,
                                             const float* __restrict__ Rb,
                                             float* __restrict__ Sb) {
  int m = threadIdx.x;
  int j2 = blockIdx.x;   // 0..7
  int dc = blockIdx.y;   // 0..3
  if (j2 == 0) {
    if (dc == 0) atomicAdd(&Sb[m], Rb[m * 8 + 0]);
    return;
  }
  float acc = 0.f;
  int d0 = dc * 128;
  for (int d = d0; d < d0 + 128; ++d) {
    size_t off = ((size_t)(j2 - 1) * 512 + d) * 512 + m;
    float tv = bf2f(P2th[off]) + bf2f(P2tl[off]);
    acc += tv * Rb[d * 8 + j2];
  }
  atomicAdd(&Sb[m], acc);
}

// ---------------- finalize: y_nat & pred ------------------------------------
__global__ __launch_bounds__(64) void finalize_kernel(
    const float* __restrict__ Cmat, const float* __restrict__ svec,
    const float* __restrict__ Qb, const float* __restrict__ yh,
    float* __restrict__ out) {
  int p = blockIdx.x;
  int lane = threadIdx.x;
  float a1 = 0.f, a2 = 0.f;
  for (int t = lane; t < 512; t += 64) {
    float cv = Cmat[(size_t)p * 512 + t];
    a1 += cv * svec[t];
    a2 += cv * Qb[t * 68 + 64];
  }
  for (int off = 32; off > 0; off >>= 1) {
    a1 += __shfl_down(a1, off);
    a2 += __shfl_down(a2, off);
  }
  if (lane == 0) {
    float ynat = yh[(size_t)(L_HIST - 1) * 256 + p] - a1;
    out[p] = ynat;
    out[256 + p] = ynat + a2;
  }
}

// ---------------- u_t weight vectors (unchanged, verified R1/R2) ------------
__global__ __launch_bounds__(256) void weights_kernel(
    const float* __restrict__ ynh, const float* __restrict__ sigma,
    const float* __restrict__ phi, const float* __restrict__ lambda_e,
    const float* __restrict__ phi_tilde, float* __restrict__ wvec,
    float* __restrict__ out) {
  int v = blockIdx.x;
  int p = threadIdx.x;
  __shared__ float w4[48];
  float val = 0.f;
  if (v == 0) {
    val = ynh[(size_t)(L_HIST - 1) * 256 + p];
    out[512 + p] = 0.f;
  } else if (v <= 16) {
    int i = v - 1;
    float s = 0.f;
    for (int j = 0; j < 24; ++j)
      s += phi_tilde[j * 16 + i] * ynh[(size_t)(L_HIST - 2 - j) * 256 + p];
    val = powf(lambda_e[i], 0.25f) * s;
  } else if (v <= 33) {
    int l = v - 17;
    float s = 0.f;
    for (int k = 0; k < 25; ++k)
      s += phi[k * 17 + l] * ynh[(size_t)(L_HIST - 1 - k) * 256 + p];
    val = powf(sigma[l], 0.25f) * s;
  } else {
    int t = v - 34;
    int i = t / 17, l = t % 17;
    if (p < 48) {
      int m = p;
      int jlo = m - 24; if (jlo < 0) jlo = 0;
      int jhi = m; if (jhi > 23) jhi = 23;
      float s = 0.f;
      for (int j = jlo; j <= jhi; ++j)
        s += phi_tilde[j * 16 + i] * phi[(m - j) * 17 + l];
      w4[p] = s;
    }
    __syncthreads();
    float s = 0.f;
    for (int m = 0; m < 48; ++m)
      s += w4[m] * ynh[(size_t)(L_HIST - 3 - m) * 256 + p];
    val = powf(lambda_e[i], 0.25f) * powf(sigma[l], 0.25f) * s;
  }
  wvec[v * 256 + p] = val;
}

// ---------------- u_t: streaming matvec sum (unchanged, verified R2) --------
__global__ __launch_bounds__(256) void ut_gemv(
    const float* __restrict__ Mtens, const float* __restrict__ Mbar,
    const float* __restrict__ wvec, float* __restrict__ out) {
  int n = blockIdx.x >> 1;
  int h = blockIdx.x & 1;
  int lane = threadIdx.x & 63;
  int wid = threadIdx.x >> 6;
  int vend = h * 153 + 153;
  float4 acc = {0.f, 0.f, 0.f, 0.f};
#pragma unroll 4
  for (int v = h * 153 + wid; v < vend; v += 4) {
    const float* mat = (v < 17 ? Mbar : Mtens - 17 * 65536) + (size_t)v * 65536;
    float4 mv = ((const float4*)(mat + (size_t)n * 256))[lane];
    float4 wv = ((const float4*)(wvec + (size_t)v * 256))[lane];
    acc.x += mv.x * wv.x; acc.y += mv.y * wv.y;
    acc.z += mv.z * wv.z; acc.w += mv.w * wv.w;
  }
  float a = (acc.x + acc.y) + (acc.z + acc.w);
  for (int off = 32; off > 0; off >>= 1) a += __shfl_down(a, off);
  if (lane == 0) atomicAdd(&out[512 + n], a);
}

// ---------------- host orchestration ----------------------------------------
extern "C" void kernel_launch(void* const* d_in, const int* in_sizes, int n_in,
                              void* d_out, int out_size, void* d_ws, size_t ws_size,
                              hipStream_t stream) {
  (void)in_sizes; (void)n_in; (void)out_size; (void)ws_size;
  const float* A   = (const float*)d_in[0];
  const float* B   = (const float*)d_in[1];
  const float* C   = (const float*)d_in[2];
  const float* M   = (const float*)d_in[3];
  const float* Mb  = (const float*)d_in[4];
  const float* sig = (const float*)d_in[5];
  const float* phi = (const float*)d_in[6];
  const float* lam = (const float*)d_in[7];
  const float* pt  = (const float*)d_in[8];
  const float* yh  = (const float*)d_in[9];
  const float* uh  = (const float*)d_in[10];
  const float* ynh = (const float*)d_in[11];
  float* out = (float*)d_out;
  char* base = (char*)d_ws;

  const size_t MB = 1u << 20;
  const size_t SL = 512 * 512;            // ushorts per plane
  ushortT* POW  = (ushortT*)base;                       // 16 slots x 1MB
  ushortT* WTh  = (ushortT*)(base + 16 * MB);           // 8192x512
  ushortT* WTl  = (ushortT*)(base + 24 * MB);
  ushortT* P1th = (ushortT*)(base + 32 * MB);           // 3584x512
  ushortT* P1tl = (ushortT*)(base + 32 * MB + 3670016);
  // P2t aliases POW slots 0..6 (N1,T1,N2,T2,N4,T4,N8 — dead after L4; P2t written L8+)
  ushortT* P2th = (ushortT*)base;
  ushortT* P2tl = (ushortT*)(base + 3670016);
  float* UT   = (float*)(base + 39 * MB);               // 68 x 8192
  float* Qb   = (float*)(base + 39 * MB + 2228224);     // 512 x 68
  float* Rb   = Qb + 512 * 68;                          // 512 x 8
  float* Sb   = Rb + 512 * 8;                           // 512
  float* wvec = Sb + 512;                               // 306 x 256

  auto ph = [&](int i) { return POW + (size_t)i * 2 * SL; };
  auto pl = [&](int i) { return POW + (size_t)i * 2 * SL + SL; };
  // slots: 0:N1 1:T1 2:N2 3:T2 4:N4 5:T4 6:N8 7:T8 8:N16 9:T16
  //        10:N32 11:N64 12:N128 13:N256 14:N512 15:N1024
  auto e1h = [&](int j) { return P1th + (size_t)(j - 1) * SL; };
  auto e1l = [&](int j) { return P1tl + (size_t)(j - 1) * SL; };
  auto e2h = [&](int j) { return P2th + (size_t)(j - 1) * SL; };
  auto e2l = [&](int j) { return P2tl + (size_t)(j - 1) * SL; };

  auto mkJ = [&](const ushortT* Ph, const ushortT* Pl, const ushortT* Qh,
                 const ushortT* Ql, ushortT* Ch, ushortT* Cl, int Mrows) {
    Job j; j.Ph = Ph; j.Pl = Pl; j.Qh = Qh; j.Ql = Ql;
    j.Ch = Ch; j.Cl = Cl; j.M = Mrows; j.tbase = 0; return j;
  };
  auto runL = [&](Job j0, Job j1, Job j2, int nj) {
    Prm p; p.j[0] = j0; p.j[1] = (nj > 1) ? j1 : j0; p.j[2] = (nj > 2) ? j2 : j0;
    p.nj = nj;
    int tb = 0;
    for (int i = 0; i < nj; ++i) { p.j[i].tbase = tb; tb += (p.j[i].M >> 7) * 4; }
    bgemm<<<tb, 256, 0, stream>>>(p);
  };

  // ---- init ----
  hipMemsetAsync(Qb, 0, (512 * 68 + 512 * 8 + 512) * sizeof(float), stream);
  split_A<<<1024, 256, 0, stream>>>(A, ph(0), pl(0), ph(1), pl(1));
  split_B<<<512, 256, 0, stream>>>(B, WTh, WTl);
  pack_ut<<<(68 * 8192) / 256, 256, 0, stream>>>(uh, UT);

  Job d = mkJ(ph(0), pl(0), ph(1), pl(1), ph(2), pl(2), 512); // dummy slot
  // ---- dual power/W/stack chain: 11 launches, 28 jobs ----
  runL(mkJ(ph(0), pl(0), ph(1), pl(1), ph(2), pl(2), 512),             // N2
       mkJ(ph(1), pl(1), ph(0), pl(0), ph(3), pl(3), 512),             // T2
       mkJ(WTh, WTl, ph(0), pl(0), WTh + 256 * 512, WTl + 256 * 512, 256), 3); // W1
  runL(mkJ(ph(2), pl(2), ph(3), pl(3), ph(4), pl(4), 512),             // N4
       mkJ(ph(3), pl(3), ph(2), pl(2), ph(5), pl(5), 512),             // T4
       mkJ(WTh, WTl, ph(2), pl(2), WTh + 512 * 512, WTl + 512 * 512, 512), 3); // W2:4
  runL(mkJ(ph(4), pl(4), ph(5), pl(5), ph(6), pl(6), 512),             // N8
       mkJ(ph(5), pl(5), ph(4), pl(4), ph(7), pl(7), 512),             // T8
       mkJ(WTh, WTl, ph(4), pl(4), WTh + 1024 * 512, WTl + 1024 * 512, 1024), 3); // W4:8
  runL(mkJ(ph(6), pl(6), ph(7), pl(7), ph(8), pl(8), 512),             // N16
       mkJ(ph(7), pl(7), ph(6), pl(6), ph(9), pl(9), 512),             // T16
       mkJ(WTh, WTl, ph(6), pl(6), WTh + 2048 * 512, WTl + 2048 * 512, 2048), 3); // W8:16
  runL(mkJ(ph(8), pl(8), ph(9), pl(9), ph(10), pl(10), 512),           // N32
       mkJ(ph(9), pl(9), ph(8), pl(8), e1h(1), e1l(1), 512),           // T32
       mkJ(WTh, WTl, ph(8), pl(8), WTh + 4096 * 512, WTl + 4096 * 512, 4096), 3); // W16:32
  runL(mkJ(ph(10), pl(10), e1h(1), e1l(1), ph(11), pl(11), 512),       // N64
       mkJ(e1h(1), e1l(1), ph(10), pl(10), e1h(2), e1l(2), 512),       // T64
       d, 2);
  runL(mkJ(ph(11), pl(11), e1h(2), e1l(2), ph(12), pl(12), 512),       // N128
       mkJ(e1h(1), e1l(1), ph(11), pl(11), e1h(3), e1l(3), 1024),      // T96,T128
       d, 2);
  runL(mkJ(ph(12), pl(12), e1h(4), e1l(4), ph(13), pl(13), 512),       // N256
       mkJ(e1h(1), e1l(1), ph(12), pl(12), e1h(5), e1l(5), 1536),      // T160..224
       mkJ(e1h(4), e1l(4), ph(12), pl(12), e2h(1), e2l(1), 512), 3);   // T256
  runL(mkJ(ph(13), pl(13), e2h(1), e2l(1), ph(14), pl(14), 512),       // N512
       mkJ(e2h(1), e2l(1), ph(13), pl(13), e2h(2), e2l(2), 512),       // T512
       d, 2);
  runL(mkJ(ph(14), pl(14), e2h(2), e2l(2), ph(15), pl(15), 512),       // N1024
       mkJ(e2h(1), e2l(1), ph(14), pl(14), e2h(3), e2l(3), 1024),      // T768,T1024
       d, 2);
  runL(mkJ(e2h(1), e2l(1), ph(15), pl(15), e2h(5), e2l(5), 1536),      // T1280..1792
       d, d, 1);

  // ---- reductions: Q, R, S, outputs ----
  qgemv<<<dim3(32, 4), 512, 0, stream>>>(WTh, WTl, UT, Qb);
  rgemv<<<dim3(8, 4), 512, 0, stream>>>(P1th, P1tl, Qb, Rb);
  sgemv<<<dim3(8, 4), 512, 0, stream>>>(P2th, P2tl, Rb, Sb);
  finalize_kernel<<<256, 64, 0, stream>>>(C, Sb, Qb, yh, out);

  // ---- u_t ----
  weights_kernel<<<306, 256, 0, stream>>>(ynh, sig, phi, lam, pt, wvec, out);
  ut_gemv<<<512, 256, 0, stream>>>(M, Mb, wvec, out);
}

// Round 4
// 359.694 us; speedup vs baseline: 2.4933x; 1.5759x over previous
//
#include <hip/hip_runtime.h>

#define L_HIST 2048
typedef unsigned short ushortT;
typedef __attribute__((ext_vector_type(8))) short bf16x8;
typedef __attribute__((ext_vector_type(4))) short bf16x4;
typedef __attribute__((ext_vector_type(16))) float f32x16;

__device__ __forceinline__ ushortT f2bf(float x) {
  union { float f; unsigned u; } v; v.f = x;
  unsigned r = (v.u + 0x7FFFu + ((v.u >> 16) & 1u)) >> 16;
  return (ushortT)r;
}
__device__ __forceinline__ float bf2f(ushortT h) {
  union { unsigned u; float f; } v; v.u = ((unsigned)h) << 16; return v.f;
}

// ---------------- job-table split-bf16 bt-GEMM, 64x64 tiles -----------------
// D[m][n] = sum_k (Ph+Pl)[m][k] * (Qh+Ql)[n][k];  K=512, N=512, ld=512.
struct Job {
  const ushortT *Ph, *Pl, *Qh, *Ql;
  ushortT *Ch, *Cl;
  int M, tbase;
};
struct Prm { Job j[3]; int nj; };

__global__ __launch_bounds__(256) void bgemm(Prm p) {
  int bx = blockIdx.x;
  int ji = 0;
  if (p.nj > 1 && bx >= p.j[1].tbase) ji = 1;
  if (p.nj > 2 && bx >= p.j[2].tbase) ji = 2;
  Job J = p.j[ji];
  int lt = bx - J.tbase;
  int mt = J.M >> 6;
  int mtile = lt % mt, ntile = lt / mt;
  size_t m0 = (size_t)mtile * 64, n0 = (size_t)ntile * 64;

  __shared__ ushortT As[2][64][36];
  __shared__ ushortT Bs[2][64][36];

  int tid = threadIdx.x;
  int lane = tid & 63, wave = tid >> 6;
  int wm = (wave & 1) * 32, wn = (wave >> 1) * 32;
  int fr = lane & 31;
  int fk = (lane >> 5) * 8;
  int row = tid >> 2;          // 0..63
  int kp = (tid & 3) * 8;      // 0,8,16,24

  f32x16 acc;
#pragma unroll
  for (int i = 0; i < 16; ++i) acc[i] = 0.f;

  const ushortT* bases[4] = {J.Ph, J.Pl, J.Qh, J.Ql};

  for (int kt = 0; kt < 512; kt += 32) {
#pragma unroll
    for (int seg = 0; seg < 4; ++seg) {
      int pl = seg & 1, isB = seg >> 1;
      const ushortT* src = bases[seg] + ((isB ? n0 : m0) + row) * 512 + kt + kp;
      bf16x8 v = *(const bf16x8*)src;
      ushortT (*dst)[36] = isB ? Bs[pl] : As[pl];
      *(bf16x4*)&dst[row][kp]     = __builtin_shufflevector(v, v, 0, 1, 2, 3);
      *(bf16x4*)&dst[row][kp + 4] = __builtin_shufflevector(v, v, 4, 5, 6, 7);
    }
    __syncthreads();
#pragma unroll
    for (int ks = 0; ks < 32; ks += 16) {
      bf16x8 af[2], bfr[2];
#pragma unroll
      for (int pl = 0; pl < 2; ++pl) {
        const ushortT* pa = &As[pl][wm + fr][ks + fk];
        bf16x4 alo = *(const bf16x4*)pa, ahi = *(const bf16x4*)(pa + 4);
        af[pl] = __builtin_shufflevector(alo, ahi, 0, 1, 2, 3, 4, 5, 6, 7);
        const ushortT* pb = &Bs[pl][wn + fr][ks + fk];
        bf16x4 blo = *(const bf16x4*)pb, bhi = *(const bf16x4*)(pb + 4);
        bfr[pl] = __builtin_shufflevector(blo, bhi, 0, 1, 2, 3, 4, 5, 6, 7);
      }
      acc = __builtin_amdgcn_mfma_f32_32x32x16_bf16(af[0], bfr[0], acc, 0, 0, 0);
      acc = __builtin_amdgcn_mfma_f32_32x32x16_bf16(af[0], bfr[1], acc, 0, 0, 0);
      acc = __builtin_amdgcn_mfma_f32_32x32x16_bf16(af[1], bfr[0], acc, 0, 0, 0);
    }
    __syncthreads();
  }
#pragma unroll
  for (int i = 0; i < 16; ++i) {
    int r = wm + (i & 3) + ((i >> 2) << 3) + ((lane >> 5) << 2);
    int c = wn + (lane & 31);
    float v = acc[i];
    ushortT h = f2bf(v);
    float rem = v - bf2f(h);
    size_t off = (m0 + r) * 512 + (n0 + c);
    J.Ch[off] = h;
    J.Cl[off] = f2bf(rem);
  }
}

// ---------------- Q = W * U via MFMA (LDS transpose-staging of WT) ----------
// Qpart[z][m][j] = sum_{k in chunk z} W[m][k]*U[k][j], 3-product split.
// WT planes: [k][m] (m-fast). UT planes: [j][k] (k-fast), 128 j rows (68 used).
__global__ __launch_bounds__(256) void qgemm(
    const ushortT* __restrict__ WTh, const ushortT* __restrict__ WTl,
    const ushortT* __restrict__ UTh, const ushortT* __restrict__ UTl,
    float* __restrict__ Qpart) {
  int z = blockIdx.x, mtile = blockIdx.y, ntile = blockIdx.z;
  int m0 = mtile * 64, n0 = ntile * 64, k0 = z * 1024;

  __shared__ ushortT As[2][64][36];
  __shared__ ushortT Bs[2][64][36];

  int tid = threadIdx.x;
  int lane = tid & 63, wave = tid >> 6;
  int wm = (wave & 1) * 32, wn = (wave >> 1) * 32;
  int fr = lane & 31;
  int fk = (lane >> 5) * 8;
  int ka = tid & 31;           // k-offset for A transpose stage
  int ma = (tid >> 5) * 8;     // m segment (8 values)
  int jb = tid >> 2;           // 0..63 B row
  int kb = (tid & 3) * 8;

  f32x16 acc;
#pragma unroll
  for (int i = 0; i < 16; ++i) acc[i] = 0.f;

  for (int kt = 0; kt < 1024; kt += 32) {
#pragma unroll
    for (int pl = 0; pl < 2; ++pl) {
      const ushortT* src = (pl ? WTl : WTh) + (size_t)(k0 + kt + ka) * 512 + m0 + ma;
      bf16x8 v = *(const bf16x8*)src;
#pragma unroll
      for (int s = 0; s < 8; ++s) As[pl][ma + s][ka] = (ushortT)v[s];
    }
#pragma unroll
    for (int pl = 0; pl < 2; ++pl) {
      const ushortT* src = (pl ? UTl : UTh) + (size_t)(n0 + jb) * 8192 + k0 + kt + kb;
      bf16x8 v = *(const bf16x8*)src;
      *(bf16x4*)&Bs[pl][jb][kb]     = __builtin_shufflevector(v, v, 0, 1, 2, 3);
      *(bf16x4*)&Bs[pl][jb][kb + 4] = __builtin_shufflevector(v, v, 4, 5, 6, 7);
    }
    __syncthreads();
#pragma unroll
    for (int ks = 0; ks < 32; ks += 16) {
      bf16x8 af[2], bfr[2];
#pragma unroll
      for (int pl = 0; pl < 2; ++pl) {
        const ushortT* pa = &As[pl][wm + fr][ks + fk];
        bf16x4 alo = *(const bf16x4*)pa, ahi = *(const bf16x4*)(pa + 4);
        af[pl] = __builtin_shufflevector(alo, ahi, 0, 1, 2, 3, 4, 5, 6, 7);
        const ushortT* pb = &Bs[pl][wn + fr][ks + fk];
        bf16x4 blo = *(const bf16x4*)pb, bhi = *(const bf16x4*)(pb + 4);
        bfr[pl] = __builtin_shufflevector(blo, bhi, 0, 1, 2, 3, 4, 5, 6, 7);
      }
      acc = __builtin_amdgcn_mfma_f32_32x32x16_bf16(af[0], bfr[0], acc, 0, 0, 0);
      acc = __builtin_amdgcn_mfma_f32_32x32x16_bf16(af[0], bfr[1], acc, 0, 0, 0);
      acc = __builtin_amdgcn_mfma_f32_32x32x16_bf16(af[1], bfr[0], acc, 0, 0, 0);
    }
    __syncthreads();
  }
#pragma unroll
  for (int i = 0; i < 16; ++i) {
    int r = wm + (i & 3) + ((i >> 2) << 3) + ((lane >> 5) << 2);
    int c = wn + (lane & 31);
    Qpart[((size_t)z * 512 + m0 + r) * 128 + n0 + c] = acc[i];
  }
}

// Qb[m][j] (ld 128) = sum_z Qpart[z][m][j], j<68
__global__ __launch_bounds__(256) void qreduce(const float* __restrict__ Qpart,
                                               float* __restrict__ Qb) {
  int idx = blockIdx.x * 256 + threadIdx.x;
  if (idx >= 512 * 68) return;
  int m = idx / 68, j = idx - m * 68;
  float s = 0.f;
#pragma unroll
  for (int z = 0; z < 8; ++z) s += Qpart[((size_t)z * 512 + m) * 128 + j];
  Qb[m * 128 + j] = s;
}

// ---------------- init / split / pack kernels -------------------------------
__global__ void split_A(const float* __restrict__ A, ushortT* N1h, ushortT* N1l,
                        ushortT* T1h, ushortT* T1l) {
  int idx = blockIdx.x * 256 + threadIdx.x;   // < 512*512
  int r = idx >> 9, c = idx & 511;
  float x = A[idx];
  ushortT h = f2bf(x); float rem = x - bf2f(h); ushortT l = f2bf(rem);
  N1h[idx] = h; N1l[idx] = l;
  T1h[c * 512 + r] = h; T1l[c * 512 + r] = l;
}

__global__ void split_B(const float* __restrict__ B, ushortT* WTh, ushortT* WTl) {
  int idx = blockIdx.x * 256 + threadIdx.x;   // < 512*256
  int d = idx >> 8, c = idx & 255;
  float x = B[idx];
  ushortT h = f2bf(x); float rem = x - bf2f(h);
  WTh[c * 512 + d] = h; WTl[c * 512 + d] = f2bf(rem);
}

// UT planes [j][k], j<128: j<64: u_rev[32j+tau][c]; j==64: tau<16 ? u_rev[tau][c]:0
__global__ void pack_ut(const float* __restrict__ uh, ushortT* __restrict__ UTh,
                        ushortT* __restrict__ UTl) {
  int idx = blockIdx.x * 256 + threadIdx.x;   // < 128*8192
  int j = idx >> 13, k = idx & 8191;
  int tau = k >> 8, c = k & 255;
  float v = 0.f;
  if (j < 64) v = uh[(size_t)(L_HIST - 1 - (32 * j + tau)) * 256 + c];
  else if (j == 64 && tau < 16) v = uh[(size_t)(L_HIST - 1 - tau) * 256 + c];
  ushortT h = f2bf(v);
  UTh[idx] = h; UTl[idx] = f2bf(v - bf2f(h));
}

// ---------------- R partials: j1=1..7 ---------------------------------------
// Rpart[(j1-1)*4+dc][m*8+j2] = sum_{d in chunk} A^{32j1}[m][d] * Qb[d][j1+8j2]
__global__ __launch_bounds__(512) void rgemm(const ushortT* __restrict__ P1th,
                                             const ushortT* __restrict__ P1tl,
                                             const float* __restrict__ Qb,
                                             float* __restrict__ Rpart) {
  int j1 = blockIdx.x + 1;     // 1..7
  int dc = blockIdx.y;         // 0..3
  int d0 = dc * 128;
  int m = threadIdx.x;
  __shared__ float Qs[128][8];
  for (int i = threadIdx.x; i < 1024; i += 512) {
    int dd = i >> 3, jj = i & 7;
    Qs[dd][jj] = Qb[(size_t)(d0 + dd) * 128 + j1 + 8 * jj];
  }
  __syncthreads();
  float acc[8];
#pragma unroll
  for (int jj = 0; jj < 8; ++jj) acc[jj] = 0.f;
  for (int d = 0; d < 128; ++d) {
    size_t off = ((size_t)(j1 - 1) * 512 + d0 + d) * 512 + m;
    float tv = bf2f(P1th[off]) + bf2f(P1tl[off]);
    float4 q0 = *(const float4*)&Qs[d][0];
    float4 q1 = *(const float4*)&Qs[d][4];
    acc[0] += tv * q0.x; acc[1] += tv * q0.y; acc[2] += tv * q0.z; acc[3] += tv * q0.w;
    acc[4] += tv * q1.x; acc[5] += tv * q1.y; acc[6] += tv * q1.z; acc[7] += tv * q1.w;
  }
  float* dst = Rpart + (size_t)((j1 - 1) * 4 + dc) * 4096 + m * 8;
#pragma unroll
  for (int jj = 0; jj < 8; ++jj) dst[jj] = acc[jj];
}

// Rb[m*8+j2] = Qb[m][8*j2] + sum_{28} Rpart
__global__ __launch_bounds__(256) void rreduce(const float* __restrict__ Qb,
                                               const float* __restrict__ Rpart,
                                               float* __restrict__ Rb) {
  int idx = blockIdx.x * 256 + threadIdx.x;   // < 4096
  int m = idx >> 3, jj = idx & 7;
  float s = Qb[(size_t)m * 128 + 8 * jj];
  for (int p = 0; p < 28; ++p) s += Rpart[(size_t)p * 4096 + idx];
  Rb[idx] = s;
}

// ---------------- S partials: j2=1..7 ---------------------------------------
__global__ __launch_bounds__(512) void sgemm(const ushortT* __restrict__ P2th,
                                             const ushortT* __restrict__ P2tl,
                                             const float* __restrict__ Rb,
                                             float* __restrict__ Spart) {
  int j2 = blockIdx.x + 1;     // 1..7
  int dc = blockIdx.y;         // 0..3
  int d0 = dc * 128;
  int m = threadIdx.x;
  __shared__ float Rs[128];
  if (threadIdx.x < 128) Rs[threadIdx.x] = Rb[(size_t)(d0 + threadIdx.x) * 8 + j2];
  __syncthreads();
  float acc = 0.f;
  for (int d = 0; d < 128; ++d) {
    size_t off = ((size_t)(j2 - 1) * 512 + d0 + d) * 512 + m;
    acc += (bf2f(P2th[off]) + bf2f(P2tl[off])) * Rs[d];
  }
  Spart[(size_t)((j2 - 1) * 4 + dc) * 512 + m] = acc;
}

__global__ __launch_bounds__(256) void sreduce(const float* __restrict__ Rb,
                                               const float* __restrict__ Spart,
                                               float* __restrict__ Sb) {
  int m = blockIdx.x * 256 + threadIdx.x;     // < 512
  float s = Rb[(size_t)m * 8];
  for (int p = 0; p < 28; ++p) s += Spart[(size_t)p * 512 + m];
  Sb[m] = s;
}

// ---------------- finalize: y_nat & pred ------------------------------------
__global__ __launch_bounds__(64) void finalize_kernel(
    const float* __restrict__ Cmat, const float* __restrict__ svec,
    const float* __restrict__ Qb, const float* __restrict__ yh,
    float* __restrict__ out) {
  int p = blockIdx.x;
  int lane = threadIdx.x;
  float a1 = 0.f, a2 = 0.f;
  for (int t = lane; t < 512; t += 64) {
    float cv = Cmat[(size_t)p * 512 + t];
    a1 += cv * svec[t];
    a2 += cv * Qb[(size_t)t * 128 + 64];
  }
  for (int off = 32; off > 0; off >>= 1) {
    a1 += __shfl_down(a1, off);
    a2 += __shfl_down(a2, off);
  }
  if (lane == 0) {
    float ynat = yh[(size_t)(L_HIST - 1) * 256 + p] - a1;
    out[p] = ynat;
    out[256 + p] = ynat + a2;
  }
}

// ---------------- u_t weight vectors (verified R1-R3) -----------------------
__global__ __launch_bounds__(256) void weights_kernel(
    const float* __restrict__ ynh, const float* __restrict__ sigma,
    const float* __restrict__ phi, const float* __restrict__ lambda_e,
    const float* __restrict__ phi_tilde, float* __restrict__ wvec,
    float* __restrict__ out) {
  int v = blockIdx.x;
  int p = threadIdx.x;
  __shared__ float w4[48];
  float val = 0.f;
  if (v == 0) {
    val = ynh[(size_t)(L_HIST - 1) * 256 + p];
    out[512 + p] = 0.f;
  } else if (v <= 16) {
    int i = v - 1;
    float s = 0.f;
    for (int j = 0; j < 24; ++j)
      s += phi_tilde[j * 16 + i] * ynh[(size_t)(L_HIST - 2 - j) * 256 + p];
    val = powf(lambda_e[i], 0.25f) * s;
  } else if (v <= 33) {
    int l = v - 17;
    float s = 0.f;
    for (int k = 0; k < 25; ++k)
      s += phi[k * 17 + l] * ynh[(size_t)(L_HIST - 1 - k) * 256 + p];
    val = powf(sigma[l], 0.25f) * s;
  } else {
    int t = v - 34;
    int i = t / 17, l = t % 17;
    if (p < 48) {
      int m = p;
      int jlo = m - 24; if (jlo < 0) jlo = 0;
      int jhi = m; if (jhi > 23) jhi = 23;
      float s = 0.f;
      for (int j = jlo; j <= jhi; ++j)
        s += phi_tilde[j * 16 + i] * phi[(m - j) * 17 + l];
      w4[p] = s;
    }
    __syncthreads();
    float s = 0.f;
    for (int m = 0; m < 48; ++m)
      s += w4[m] * ynh[(size_t)(L_HIST - 3 - m) * 256 + p];
    val = powf(lambda_e[i], 0.25f) * powf(sigma[l], 0.25f) * s;
  }
  wvec[v * 256 + p] = val;
}

// ---------------- u_t: streaming matvec sum (verified R2/R3) ----------------
__global__ __launch_bounds__(256) void ut_gemv(
    const float* __restrict__ Mtens, const float* __restrict__ Mbar,
    const float* __restrict__ wvec, float* __restrict__ out) {
  int n = blockIdx.x >> 1;
  int h = blockIdx.x & 1;
  int lane = threadIdx.x & 63;
  int wid = threadIdx.x >> 6;
  int vend = h * 153 + 153;
  float4 acc = {0.f, 0.f, 0.f, 0.f};
#pragma unroll 4
  for (int v = h * 153 + wid; v < vend; v += 4) {
    const float* mat = (v < 17 ? Mbar : Mtens - 17 * 65536) + (size_t)v * 65536;
    float4 mv = ((const float4*)(mat + (size_t)n * 256))[lane];
    float4 wv = ((const float4*)(wvec + (size_t)v * 256))[lane];
    acc.x += mv.x * wv.x; acc.y += mv.y * wv.y;
    acc.z += mv.z * wv.z; acc.w += mv.w * wv.w;
  }
  float a = (acc.x + acc.y) + (acc.z + acc.w);
  for (int off = 32; off > 0; off >>= 1) a += __shfl_down(a, off);
  if (lane == 0) atomicAdd(&out[512 + n], a);
}

// ---------------- host orchestration ----------------------------------------
extern "C" void kernel_launch(void* const* d_in, const int* in_sizes, int n_in,
                              void* d_out, int out_size, void* d_ws, size_t ws_size,
                              hipStream_t stream) {
  (void)in_sizes; (void)n_in; (void)out_size; (void)ws_size;
  const float* A   = (const float*)d_in[0];
  const float* B   = (const float*)d_in[1];
  const float* C   = (const float*)d_in[2];
  const float* M   = (const float*)d_in[3];
  const float* Mb  = (const float*)d_in[4];
  const float* sig = (const float*)d_in[5];
  const float* phi = (const float*)d_in[6];
  const float* lam = (const float*)d_in[7];
  const float* pt  = (const float*)d_in[8];
  const float* yh  = (const float*)d_in[9];
  const float* uh  = (const float*)d_in[10];
  const float* ynh = (const float*)d_in[11];
  float* out = (float*)d_out;
  char* base = (char*)d_ws;

  const size_t MB = 1u << 20;
  const size_t SL = 512 * 512;            // ushorts per plane
  ushortT* POW  = (ushortT*)base;                       // 16 slots x 1MB
  ushortT* WTh  = (ushortT*)(base + 16 * MB);           // 8192x512 (8MB)
  ushortT* WTl  = (ushortT*)(base + 24 * MB);
  ushortT* P1th = (ushortT*)(base + 32 * MB);           // 3584x512 (3.5MB)
  ushortT* P1tl = (ushortT*)(base + 32 * MB + 3670016);
  // aliases of dead POW slots (safe by chain liveness):
  ushortT* P2th = (ushortT*)base;                       // slots 0-3.5 (dead after L2-L4)
  ushortT* P2tl = (ushortT*)(base + 3670016);
  ushortT* UTh  = (ushortT*)(base + 8 * MB);            // slots 8-9 (dead after L5)
  ushortT* UTl  = (ushortT*)(base + 10 * MB);           // slots 10-11 (dead after L7)
  float*   Qpart= (float*)(base + 12 * MB);             // slots 12-13 (dead after L9), 2MB
  float* Qb    = (float*)(base + 39 * MB);              // 512x128 (256KB)
  float* Rpart = Qb + 512 * 128;                        // 28x4096 (448KB)
  float* Rb    = Rpart + 28 * 4096;                     // 4096
  float* Spart = Rb + 4096;                             // 28x512
  float* Sb    = Spart + 28 * 512;                      // 512
  float* wvec  = Sb + 512;                              // 306x256

  auto ph = [&](int i) { return POW + (size_t)i * 2 * SL; };
  auto pl = [&](int i) { return POW + (size_t)i * 2 * SL + SL; };
  auto e1h = [&](int j) { return P1th + (size_t)(j - 1) * SL; };
  auto e1l = [&](int j) { return P1tl + (size_t)(j - 1) * SL; };
  auto e2h = [&](int j) { return P2th + (size_t)(j - 1) * SL; };
  auto e2l = [&](int j) { return P2tl + (size_t)(j - 1) * SL; };

  auto mkJ = [&](const ushortT* Ph, const ushortT* Pl, const ushortT* Qh,
                 const ushortT* Ql, ushortT* Ch, ushortT* Cl, int Mrows) {
    Job j; j.Ph = Ph; j.Pl = Pl; j.Qh = Qh; j.Ql = Ql;
    j.Ch = Ch; j.Cl = Cl; j.M = Mrows; j.tbase = 0; return j;
  };
  auto runL = [&](Job j0, Job j1, Job j2, int nj) {
    Prm p; p.j[0] = j0; p.j[1] = (nj > 1) ? j1 : j0; p.j[2] = (nj > 2) ? j2 : j0;
    p.nj = nj;
    int tb = 0;
    for (int i = 0; i < nj; ++i) { p.j[i].tbase = tb; tb += (p.j[i].M >> 6) * 8; }
    bgemm<<<tb, 256, 0, stream>>>(p);
  };

  // ---- init ----
  split_A<<<1024, 256, 0, stream>>>(A, ph(0), pl(0), ph(1), pl(1));
  split_B<<<512, 256, 0, stream>>>(B, WTh, WTl);

  Job d = mkJ(ph(0), pl(0), ph(1), pl(1), ph(2), pl(2), 512); // dummy
  // ---- dual power/W/stack chain: 11 launches (same jobs as R3, 64-tiles) ----
  runL(mkJ(ph(0), pl(0), ph(1), pl(1), ph(2), pl(2), 512),             // N2
       mkJ(ph(1), pl(1), ph(0), pl(0), ph(3), pl(3), 512),             // T2
       mkJ(WTh, WTl, ph(0), pl(0), WTh + 256 * 512, WTl + 256 * 512, 256), 3); // W1
  runL(mkJ(ph(2), pl(2), ph(3), pl(3), ph(4), pl(4), 512),             // N4
       mkJ(ph(3), pl(3), ph(2), pl(2), ph(5), pl(5), 512),             // T4
       mkJ(WTh, WTl, ph(2), pl(2), WTh + 512 * 512, WTl + 512 * 512, 512), 3); // W2:4
  runL(mkJ(ph(4), pl(4), ph(5), pl(5), ph(6), pl(6), 512),             // N8
       mkJ(ph(5), pl(5), ph(4), pl(4), ph(7), pl(7), 512),             // T8
       mkJ(WTh, WTl, ph(4), pl(4), WTh + 1024 * 512, WTl + 1024 * 512, 1024), 3); // W4:8
  runL(mkJ(ph(6), pl(6), ph(7), pl(7), ph(8), pl(8), 512),             // N16
       mkJ(ph(7), pl(7), ph(6), pl(6), ph(9), pl(9), 512),             // T16
       mkJ(WTh, WTl, ph(6), pl(6), WTh + 2048 * 512, WTl + 2048 * 512, 2048), 3); // W8:16
  runL(mkJ(ph(8), pl(8), ph(9), pl(9), ph(10), pl(10), 512),           // N32
       mkJ(ph(9), pl(9), ph(8), pl(8), e1h(1), e1l(1), 512),           // T32
       mkJ(WTh, WTl, ph(8), pl(8), WTh + 4096 * 512, WTl + 4096 * 512, 4096), 3); // W16:32
  runL(mkJ(ph(10), pl(10), e1h(1), e1l(1), ph(11), pl(11), 512),       // N64
       mkJ(e1h(1), e1l(1), ph(10), pl(10), e1h(2), e1l(2), 512),       // T64
       d, 2);
  runL(mkJ(ph(11), pl(11), e1h(2), e1l(2), ph(12), pl(12), 512),       // N128
       mkJ(e1h(1), e1l(1), ph(11), pl(11), e1h(3), e1l(3), 1024),      // T96,T128
       d, 2);
  runL(mkJ(ph(12), pl(12), e1h(4), e1l(4), ph(13), pl(13), 512),       // N256
       mkJ(e1h(1), e1l(1), ph(12), pl(12), e1h(5), e1l(5), 1536),      // T160..224
       mkJ(e1h(4), e1l(4), ph(12), pl(12), e2h(1), e2l(1), 512), 3);   // T256
  runL(mkJ(ph(13), pl(13), e2h(1), e2l(1), ph(14), pl(14), 512),       // N512
       mkJ(e2h(1), e2l(1), ph(13), pl(13), e2h(2), e2l(2), 512),       // T512
       d, 2);
  runL(mkJ(ph(14), pl(14), e2h(2), e2l(2), ph(15), pl(15), 512),       // N1024
       mkJ(e2h(1), e2l(1), ph(14), pl(14), e2h(3), e2l(3), 1024),      // T768,T1024
       d, 2);
  runL(mkJ(e2h(1), e2l(1), ph(15), pl(15), e2h(5), e2l(5), 1536),      // T1280..1792
       d, d, 1);

  // ---- Q / R / S reductions (after chain; UT & Qpart alias dead slots) ----
  pack_ut<<<4096, 256, 0, stream>>>(uh, UTh, UTl);
  qgemm<<<dim3(8, 8, 2), 256, 0, stream>>>(WTh, WTl, UTh, UTl, Qpart);
  qreduce<<<136, 256, 0, stream>>>(Qpart, Qb);
  rgemm<<<dim3(7, 4), 512, 0, stream>>>(P1th, P1tl, Qb, Rpart);
  rreduce<<<16, 256, 0, stream>>>(Qb, Rpart, Rb);
  sgemm<<<dim3(7, 4), 512, 0, stream>>>(P2th, P2tl, Rb, Spart);
  sreduce<<<2, 256, 0, stream>>>(Rb, Spart, Sb);
  finalize_kernel<<<256, 64, 0, stream>>>(C, Sb, Qb, yh, out);

  // ---- u_t ----
  weights_kernel<<<306, 256, 0, stream>>>(ynh, sig, phi, lam, pt, wvec, out);
  ut_gemv<<<512, 256, 0, stream>>>(M, Mb, wvec, out);
}

// Round 5
// 326.526 us; speedup vs baseline: 2.7466x; 1.1016x over previous
//
#include <hip/hip_runtime.h>

#define L_HIST 2048
typedef unsigned short ushortT;
typedef __attribute__((ext_vector_type(8))) short bf16x8;
typedef __attribute__((ext_vector_type(4))) short bf16x4;
typedef __attribute__((ext_vector_type(16))) float f32x16;

__device__ __forceinline__ ushortT f2bf(float x) {
  union { float f; unsigned u; } v; v.f = x;
  unsigned r = (v.u + 0x7FFFu + ((v.u >> 16) & 1u)) >> 16;
  return (ushortT)r;
}
__device__ __forceinline__ float bf2f(ushortT h) {
  union { unsigned u; float f; } v; v.u = ((unsigned)h) << 16; return v.f;
}
__device__ __forceinline__ bf16x4 lo4(bf16x8 v) {
  return __builtin_shufflevector(v, v, 0, 1, 2, 3);
}
__device__ __forceinline__ bf16x4 hi4(bf16x8 v) {
  return __builtin_shufflevector(v, v, 4, 5, 6, 7);
}
__device__ __forceinline__ bf16x8 rd8(const ushortT* p) {
  bf16x4 a = *(const bf16x4*)p, b = *(const bf16x4*)(p + 4);
  return __builtin_shufflevector(a, b, 0, 1, 2, 3, 4, 5, 6, 7);
}

// ---------------- job-table 2-product bf16 bt-GEMM, dbuf, 64x64 tiles -------
// D[m][n] = sum_k Ph[m][k] * (Qh+Ql)[n][k];  K=512, ld=512.
// Ch always; Cl (lo plane) and Cf (fp32 copy) optional.
struct Job {
  const ushortT *Ph, *Qh, *Ql;
  ushortT *Ch, *Cl;
  float *Cf;
  int M, tbase;
};
struct Prm { Job j[3]; int nj; };

__global__ __launch_bounds__(256) void bgemm(Prm p) {
  int bx = blockIdx.x;
  int ji = 0;
  if (p.nj > 1 && bx >= p.j[1].tbase) ji = 1;
  if (p.nj > 2 && bx >= p.j[2].tbase) ji = 2;
  Job J = p.j[ji];
  int lt = bx - J.tbase;
  int mt = J.M >> 6;
  int mtile = lt % mt, ntile = lt / mt;
  size_t m0 = (size_t)mtile * 64, n0 = (size_t)ntile * 64;

  __shared__ ushortT As[2][64][36];
  __shared__ ushortT Bhs[2][64][36];
  __shared__ ushortT Bls[2][64][36];

  int tid = threadIdx.x;
  int lane = tid & 63, wave = tid >> 6;
  int wm = (wave & 1) * 32, wn = (wave >> 1) * 32;
  int fr = lane & 31, fk = (lane >> 5) * 8;
  int row = tid >> 2, kp = (tid & 3) * 8;

  const ushortT* pA  = J.Ph + (m0 + row) * 512 + kp;
  const ushortT* pBh = J.Qh + (n0 + row) * 512 + kp;
  const ushortT* pBl = J.Ql + (n0 + row) * 512 + kp;

  bf16x8 rA  = *(const bf16x8*)pA;
  bf16x8 rBh = *(const bf16x8*)pBh;
  bf16x8 rBl = *(const bf16x8*)pBl;

  f32x16 acc;
#pragma unroll
  for (int i = 0; i < 16; ++i) acc[i] = 0.f;

  for (int kt = 0; kt < 512; kt += 32) {
    int buf = (kt >> 5) & 1;
    *(bf16x4*)&As[buf][row][kp]      = lo4(rA);
    *(bf16x4*)&As[buf][row][kp + 4]  = hi4(rA);
    *(bf16x4*)&Bhs[buf][row][kp]     = lo4(rBh);
    *(bf16x4*)&Bhs[buf][row][kp + 4] = hi4(rBh);
    *(bf16x4*)&Bls[buf][row][kp]     = lo4(rBl);
    *(bf16x4*)&Bls[buf][row][kp + 4] = hi4(rBl);
    __syncthreads();
    if (kt + 32 < 512) {
      rA  = *(const bf16x8*)(pA + kt + 32);
      rBh = *(const bf16x8*)(pBh + kt + 32);
      rBl = *(const bf16x8*)(pBl + kt + 32);
    }
#pragma unroll
    for (int ks = 0; ks < 32; ks += 16) {
      bf16x8 a  = rd8(&As[buf][wm + fr][ks + fk]);
      bf16x8 bh = rd8(&Bhs[buf][wn + fr][ks + fk]);
      bf16x8 bl = rd8(&Bls[buf][wn + fr][ks + fk]);
      acc = __builtin_amdgcn_mfma_f32_32x32x16_bf16(a, bh, acc, 0, 0, 0);
      acc = __builtin_amdgcn_mfma_f32_32x32x16_bf16(a, bl, acc, 0, 0, 0);
    }
  }
#pragma unroll
  for (int i = 0; i < 16; ++i) {
    int r = wm + (i & 3) + ((i >> 2) << 3) + ((lane >> 5) << 2);
    int c = wn + (lane & 31);
    float v = acc[i];
    size_t off = (m0 + r) * 512 + (n0 + c);
    ushortT h = f2bf(v);
    J.Ch[off] = h;
    if (J.Cl) J.Cl[off] = f2bf(v - bf2f(h));
    if (J.Cf) J.Cf[off] = v;
  }
}

// ---------------- Q = W * U via MFMA, dbuf, LDS transpose stage for W -------
// Qpart[z][m][j] = sum_{k in z-chunk} Wh[m][k]*(Uh+Ul)[k][j]
__global__ __launch_bounds__(256) void qgemm(
    const ushortT* __restrict__ WTh, const ushortT* __restrict__ UTh,
    const ushortT* __restrict__ UTl, float* __restrict__ Qpart) {
  int z = blockIdx.x, mtile = blockIdx.y, ntile = blockIdx.z;
  int m0 = mtile * 64, n0 = ntile * 64, k0 = z * 1024;

  __shared__ ushortT As[2][64][36];
  __shared__ ushortT Bhs[2][64][36];
  __shared__ ushortT Bls[2][64][36];

  int tid = threadIdx.x;
  int lane = tid & 63, wave = tid >> 6;
  int wm = (wave & 1) * 32, wn = (wave >> 1) * 32;
  int fr = lane & 31, fk = (lane >> 5) * 8;
  int ka = tid & 31, ma = (tid >> 5) * 8;
  int jb = tid >> 2, kb = (tid & 3) * 8;

  const ushortT* pW  = WTh + (size_t)(k0 + ka) * 512 + m0 + ma;
  const ushortT* pUh = UTh + (size_t)(n0 + jb) * 8192 + k0 + kb;
  const ushortT* pUl = UTl + (size_t)(n0 + jb) * 8192 + k0 + kb;

  bf16x8 rW  = *(const bf16x8*)pW;
  bf16x8 rUh = *(const bf16x8*)pUh;
  bf16x8 rUl = *(const bf16x8*)pUl;

  f32x16 acc;
#pragma unroll
  for (int i = 0; i < 16; ++i) acc[i] = 0.f;

  for (int kt = 0; kt < 1024; kt += 32) {
    int buf = (kt >> 5) & 1;
#pragma unroll
    for (int s = 0; s < 8; ++s) As[buf][ma + s][ka] = (ushortT)rW[s];
    *(bf16x4*)&Bhs[buf][jb][kb]     = lo4(rUh);
    *(bf16x4*)&Bhs[buf][jb][kb + 4] = hi4(rUh);
    *(bf16x4*)&Bls[buf][jb][kb]     = lo4(rUl);
    *(bf16x4*)&Bls[buf][jb][kb + 4] = hi4(rUl);
    __syncthreads();
    if (kt + 32 < 1024) {
      rW  = *(const bf16x8*)(pW + (size_t)(kt + 32) * 512);
      rUh = *(const bf16x8*)(pUh + kt + 32);
      rUl = *(const bf16x8*)(pUl + kt + 32);
    }
#pragma unroll
    for (int ks = 0; ks < 32; ks += 16) {
      bf16x8 a  = rd8(&As[buf][wm + fr][ks + fk]);
      bf16x8 bh = rd8(&Bhs[buf][wn + fr][ks + fk]);
      bf16x8 bl = rd8(&Bls[buf][wn + fr][ks + fk]);
      acc = __builtin_amdgcn_mfma_f32_32x32x16_bf16(a, bh, acc, 0, 0, 0);
      acc = __builtin_amdgcn_mfma_f32_32x32x16_bf16(a, bl, acc, 0, 0, 0);
    }
  }
#pragma unroll
  for (int i = 0; i < 16; ++i) {
    int r = wm + (i & 3) + ((i >> 2) << 3) + ((lane >> 5) << 2);
    int c = wn + (lane & 31);
    Qpart[((size_t)z * 512 + m0 + r) * 128 + n0 + c] = acc[i];
  }
}

// ---------------- fused init: split A, split B(hi), pack U ------------------
__global__ void init_all(const float* __restrict__ A, const float* __restrict__ B,
                         const float* __restrict__ uh,
                         ushortT* N1h, ushortT* N1l, ushortT* T1h, ushortT* T1l,
                         ushortT* WTh, ushortT* UTh, ushortT* UTl) {
  int idx = blockIdx.x * 256 + threadIdx.x;
  if (idx < 262144) {
    int r = idx >> 9, c = idx & 511;
    float x = A[idx];
    ushortT h = f2bf(x); ushortT l = f2bf(x - bf2f(h));
    N1h[idx] = h; N1l[idx] = l;
    T1h[c * 512 + r] = h; T1l[c * 512 + r] = l;
  } else if (idx < 262144 + 131072) {
    int i2 = idx - 262144;
    int d = i2 >> 8, c = i2 & 255;
    WTh[c * 512 + d] = f2bf(B[i2]);
  } else {
    int i2 = idx - 393216;          // < 128*8192
    int j = i2 >> 13, k = i2 & 8191;
    int tau = k >> 8, c = k & 255;
    float v = 0.f;
    if (j < 64) v = uh[(size_t)(L_HIST - 1 - (32 * j + tau)) * 256 + c];
    else if (j == 64 && tau < 16) v = uh[(size_t)(L_HIST - 1 - tau) * 256 + c];
    ushortT h = f2bf(v);
    UTh[i2] = h; UTl[i2] = f2bf(v - bf2f(h));
  }
}

// ---------------- R partials (reads fp32 stacks + Qpart inline) -------------
__global__ __launch_bounds__(512) void rgemm(const float* __restrict__ Pf1,
                                             const float* __restrict__ Qpart,
                                             float* __restrict__ Rpart) {
  int j1 = blockIdx.x + 1;     // 1..7
  int dc = blockIdx.y;         // 0..3
  int d0 = dc * 128;
  int m = threadIdx.x;
  __shared__ float Qs[128][8];
  for (int i = threadIdx.x; i < 1024; i += 512) {
    int dd = i >> 3, jj = i & 7;
    float s = 0.f;
#pragma unroll
    for (int z = 0; z < 8; ++z)
      s += Qpart[((size_t)z * 512 + d0 + dd) * 128 + j1 + 8 * jj];
    Qs[dd][jj] = s;
  }
  __syncthreads();
  float acc[8];
#pragma unroll
  for (int jj = 0; jj < 8; ++jj) acc[jj] = 0.f;
  for (int d = 0; d < 128; ++d) {
    float tv = Pf1[((size_t)(j1 - 1) * 512 + d0 + d) * 512 + m];
    float4 q0 = *(const float4*)&Qs[d][0];
    float4 q1 = *(const float4*)&Qs[d][4];
    acc[0] += tv * q0.x; acc[1] += tv * q0.y; acc[2] += tv * q0.z; acc[3] += tv * q0.w;
    acc[4] += tv * q1.x; acc[5] += tv * q1.y; acc[6] += tv * q1.z; acc[7] += tv * q1.w;
  }
  float* dst = Rpart + (size_t)((j1 - 1) * 4 + dc) * 4096 + m * 8;
#pragma unroll
  for (int jj = 0; jj < 8; ++jj) dst[jj] = acc[jj];
}

// ---------------- S partials (assembles Rb rows inline) ---------------------
__global__ __launch_bounds__(512) void sgemm(const float* __restrict__ Pf2,
                                             const float* __restrict__ Qpart,
                                             const float* __restrict__ Rpart,
                                             float* __restrict__ Spart) {
  int j2 = blockIdx.x + 1;     // 1..7
  int dc = blockIdx.y;         // 0..3
  int d0 = dc * 128;
  int m = threadIdx.x;
  __shared__ float Rs[128];
  if (threadIdx.x < 128) {
    int dd = threadIdx.x;
    float s = 0.f;
#pragma unroll
    for (int z = 0; z < 8; ++z)
      s += Qpart[((size_t)z * 512 + d0 + dd) * 128 + 8 * j2];
    for (int p = 0; p < 28; ++p)
      s += Rpart[(size_t)p * 4096 + (d0 + dd) * 8 + j2];
    Rs[dd] = s;
  }
  __syncthreads();
  float acc = 0.f;
  for (int d = 0; d < 128; ++d)
    acc += Pf2[((size_t)(j2 - 1) * 512 + d0 + d) * 512 + m] * Rs[d];
  Spart[(size_t)((j2 - 1) * 4 + dc) * 512 + m] = acc;
}

// ---------------- finalize: y_nat & pred (assembles s inline) ---------------
__global__ __launch_bounds__(64) void finalize_kernel(
    const float* __restrict__ Cmat, const float* __restrict__ Qpart,
    const float* __restrict__ Rpart, const float* __restrict__ Spart,
    const float* __restrict__ yh, float* __restrict__ out) {
  int p = blockIdx.x;
  int lane = threadIdx.x;
  float a1 = 0.f, a2 = 0.f;
  for (int t = lane; t < 512; t += 64) {
    float sb = 0.f, qp = 0.f;
#pragma unroll
    for (int z = 0; z < 8; ++z) {
      sb += Qpart[((size_t)z * 512 + t) * 128 + 0];
      qp += Qpart[((size_t)z * 512 + t) * 128 + 64];
    }
    for (int q = 0; q < 28; ++q) {
      sb += Rpart[(size_t)q * 4096 + t * 8];
      sb += Spart[(size_t)q * 512 + t];
    }
    float cv = Cmat[(size_t)p * 512 + t];
    a1 += cv * sb;
    a2 += cv * qp;
  }
  for (int off = 32; off > 0; off >>= 1) {
    a1 += __shfl_down(a1, off);
    a2 += __shfl_down(a2, off);
  }
  if (lane == 0) {
    float ynat = yh[(size_t)(L_HIST - 1) * 256 + p] - a1;
    out[p] = ynat;
    out[256 + p] = ynat + a2;
  }
}

// ---------------- u_t weight vectors (verified R1-R4) -----------------------
__global__ __launch_bounds__(256) void weights_kernel(
    const float* __restrict__ ynh, const float* __restrict__ sigma,
    const float* __restrict__ phi, const float* __restrict__ lambda_e,
    const float* __restrict__ phi_tilde, float* __restrict__ wvec,
    float* __restrict__ out) {
  int v = blockIdx.x;
  int p = threadIdx.x;
  __shared__ float w4[48];
  float val = 0.f;
  if (v == 0) {
    val = ynh[(size_t)(L_HIST - 1) * 256 + p];
    out[512 + p] = 0.f;
  } else if (v <= 16) {
    int i = v - 1;
    float s = 0.f;
    for (int j = 0; j < 24; ++j)
      s += phi_tilde[j * 16 + i] * ynh[(size_t)(L_HIST - 2 - j) * 256 + p];
    val = powf(lambda_e[i], 0.25f) * s;
  } else if (v <= 33) {
    int l = v - 17;
    float s = 0.f;
    for (int k = 0; k < 25; ++k)
      s += phi[k * 17 + l] * ynh[(size_t)(L_HIST - 1 - k) * 256 + p];
    val = powf(sigma[l], 0.25f) * s;
  } else {
    int t = v - 34;
    int i = t / 17, l = t % 17;
    if (p < 48) {
      int m = p;
      int jlo = m - 24; if (jlo < 0) jlo = 0;
      int jhi = m; if (jhi > 23) jhi = 23;
      float s = 0.f;
      for (int j = jlo; j <= jhi; ++j)
        s += phi_tilde[j * 16 + i] * phi[(m - j) * 17 + l];
      w4[p] = s;
    }
    __syncthreads();
    float s = 0.f;
    for (int m = 0; m < 48; ++m)
      s += w4[m] * ynh[(size_t)(L_HIST - 3 - m) * 256 + p];
    val = powf(lambda_e[i], 0.25f) * powf(sigma[l], 0.25f) * s;
  }
  wvec[v * 256 + p] = val;
}

// ---------------- u_t: streaming matvec sum, 4-way v split ------------------
__global__ __launch_bounds__(256) void ut_gemv(
    const float* __restrict__ Mtens, const float* __restrict__ Mbar,
    const float* __restrict__ wvec, float* __restrict__ out) {
  int n = blockIdx.x & 255;
  int h = blockIdx.x >> 8;     // 0..3
  int lane = threadIdx.x & 63;
  int wid = threadIdx.x >> 6;
  int vs = (306 * h) >> 2, ve = (306 * (h + 1)) >> 2;
  float4 acc = {0.f, 0.f, 0.f, 0.f};
#pragma unroll 4
  for (int v = vs + wid; v < ve; v += 4) {
    const float* mat = (v < 17 ? Mbar : Mtens - 17 * 65536) + (size_t)v * 65536;
    float4 mv = ((const float4*)(mat + (size_t)n * 256))[lane];
    float4 wv = ((const float4*)(wvec + (size_t)v * 256))[lane];
    acc.x += mv.x * wv.x; acc.y += mv.y * wv.y;
    acc.z += mv.z * wv.z; acc.w += mv.w * wv.w;
  }
  float a = (acc.x + acc.y) + (acc.z + acc.w);
  for (int off = 32; off > 0; off >>= 1) a += __shfl_down(a, off);
  if (lane == 0) atomicAdd(&out[512 + n], a);
}

// ---------------- host orchestration ----------------------------------------
extern "C" void kernel_launch(void* const* d_in, const int* in_sizes, int n_in,
                              void* d_out, int out_size, void* d_ws, size_t ws_size,
                              hipStream_t stream) {
  (void)in_sizes; (void)n_in; (void)out_size; (void)ws_size;
  const float* A   = (const float*)d_in[0];
  const float* B   = (const float*)d_in[1];
  const float* C   = (const float*)d_in[2];
  const float* M   = (const float*)d_in[3];
  const float* Mb  = (const float*)d_in[4];
  const float* sig = (const float*)d_in[5];
  const float* phi = (const float*)d_in[6];
  const float* lam = (const float*)d_in[7];
  const float* pt  = (const float*)d_in[8];
  const float* yh  = (const float*)d_in[9];
  const float* uh  = (const float*)d_in[10];
  const float* ynh = (const float*)d_in[11];
  float* out = (float*)d_out;
  char* base = (char*)d_ws;

  const size_t MB = 1u << 20;
  const size_t SL = 512 * 512;            // elems per 512x512 plane
  ushortT* POW  = (ushortT*)base;                 // 16 slots x (hi+lo) = 16 MB
  ushortT* WTh  = (ushortT*)(base + 16 * MB);     // 8192x512 (8 MB)
  ushortT* P1th = (ushortT*)(base + 26 * MB);     // 7 x SL
  ushortT* P1tl = (ushortT*)(base + 30 * MB);
  ushortT* P2th = (ushortT*)(base + 34 * MB);
  ushortT* P2tl = (ushortT*)(base + 38 * MB);
  float*   Pf1  = (float*)(base + 42 * MB);       // 7 x SL fp32
  float*   Pf2  = (float*)(base + 50 * MB);
  ushortT* UTh  = (ushortT*)(base + 58 * MB);     // 128x8192 (2 MB)
  ushortT* UTl  = (ushortT*)(base + 60 * MB);
  float*   Qpart= (float*)(base + 62 * MB);       // 8x512x128 (2 MB)
  float*   Rpart= (float*)(base + 64 * MB);       // 28x4096
  float*   Spart= Rpart + 28 * 4096;              // 28x512
  float*   wvec = Spart + 28 * 512;               // 306x256

  auto ph = [&](int i) { return POW + (size_t)i * 2 * SL; };
  auto pl = [&](int i) { return POW + (size_t)i * 2 * SL + SL; };
  // slots: 0:N1 1:T1 2:N2 3:T2 4:N4 5:T4 6:N8 7:T8 8:N16 9:T16
  //        10:N32 11:N64 12:N128 13:N256 14:N512 15:N1024
  auto e1h = [&](int j) { return P1th + (size_t)(j - 1) * SL; };
  auto e1l = [&](int j) { return P1tl + (size_t)(j - 1) * SL; };
  auto e2h = [&](int j) { return P2th + (size_t)(j - 1) * SL; };
  auto e2l = [&](int j) { return P2tl + (size_t)(j - 1) * SL; };

  auto mkJ = [&](const ushortT* Ph, const ushortT* Qh, const ushortT* Ql,
                 ushortT* Ch, ushortT* Cl, float* Cf, int Mrows) {
    Job j; j.Ph = Ph; j.Qh = Qh; j.Ql = Ql;
    j.Ch = Ch; j.Cl = Cl; j.Cf = Cf; j.M = Mrows; j.tbase = 0; return j;
  };
  auto runL = [&](Job j0, Job j1, Job j2, int nj) {
    Prm p; p.j[0] = j0; p.j[1] = (nj > 1) ? j1 : j0; p.j[2] = (nj > 2) ? j2 : j0;
    p.nj = nj;
    int tb = 0;
    for (int i = 0; i < nj; ++i) { p.j[i].tbase = tb; tb += (p.j[i].M >> 6) * 8; }
    bgemm<<<tb, 256, 0, stream>>>(p);
  };

  // ---- init (one node) ----
  init_all<<<5632, 256, 0, stream>>>(A, B, uh, ph(0), pl(0), ph(1), pl(1),
                                     WTh, UTh, UTl);

  Job d = mkJ(ph(0), ph(1), pl(1), ph(2), pl(2), nullptr, 512); // dummy
  // ---- dual power/W/stack chain: 11 launches ----
  runL(mkJ(ph(0), ph(1), pl(1), ph(2), pl(2), nullptr, 512),              // N2
       mkJ(ph(1), ph(0), pl(0), ph(3), pl(3), nullptr, 512),              // T2
       mkJ(WTh, ph(0), pl(0), WTh + 256 * 512, nullptr, nullptr, 256), 3);// W1
  runL(mkJ(ph(2), ph(3), pl(3), ph(4), pl(4), nullptr, 512),              // N4
       mkJ(ph(3), ph(2), pl(2), ph(5), pl(5), nullptr, 512),              // T4
       mkJ(WTh, ph(2), pl(2), WTh + 512 * 512, nullptr, nullptr, 512), 3);// W2:4
  runL(mkJ(ph(4), ph(5), pl(5), ph(6), pl(6), nullptr, 512),              // N8
       mkJ(ph(5), ph(4), pl(4), ph(7), pl(7), nullptr, 512),              // T8
       mkJ(WTh, ph(4), pl(4), WTh + 1024 * 512, nullptr, nullptr, 1024), 3); // W4:8
  runL(mkJ(ph(6), ph(7), pl(7), ph(8), pl(8), nullptr, 512),              // N16
       mkJ(ph(7), ph(6), pl(6), ph(9), pl(9), nullptr, 512),              // T16
       mkJ(WTh, ph(6), pl(6), WTh + 2048 * 512, nullptr, nullptr, 2048), 3); // W8:16
  runL(mkJ(ph(8), ph(9), pl(9), ph(10), pl(10), nullptr, 512),            // N32
       mkJ(ph(9), ph(8), pl(8), e1h(1), e1l(1), Pf1, 512),                // T32
       mkJ(WTh, ph(8), pl(8), WTh + 4096 * 512, nullptr, nullptr, 4096), 3); // W16:32
  runL(mkJ(ph(10), e1h(1), e1l(1), ph(11), pl(11), nullptr, 512),         // N64
       mkJ(e1h(1), ph(10), pl(10), e1h(2), e1l(2), Pf1 + SL, 512),        // T64
       d, 2);
  runL(mkJ(ph(11), e1h(2), e1l(2), ph(12), pl(12), nullptr, 512),         // N128
       mkJ(e1h(1), ph(11), pl(11), e1h(3), e1l(3), Pf1 + 2 * SL, 1024),   // T96,T128
       d, 2);
  runL(mkJ(ph(12), e1h(4), e1l(4), ph(13), pl(13), nullptr, 512),         // N256
       mkJ(e1h(1), ph(12), pl(12), e1h(5), nullptr, Pf1 + 4 * SL, 1536),  // T160..224
       mkJ(e1h(4), ph(12), pl(12), e2h(1), e2l(1), Pf2, 512), 3);         // T256
  runL(mkJ(ph(13), e2h(1), e2l(1), ph(14), pl(14), nullptr, 512),         // N512
       mkJ(e2h(1), ph(13), pl(13), e2h(2), e2l(2), Pf2 + SL, 512),        // T512
       d, 2);
  runL(mkJ(ph(14), e2h(2), e2l(2), ph(15), pl(15), nullptr, 512),         // N1024
       mkJ(e2h(1), ph(14), pl(14), e2h(3), nullptr, Pf2 + 2 * SL, 1024),  // T768,T1024
       d, 2);
  runL(mkJ(e2h(1), ph(15), pl(15), e2h(5), nullptr, Pf2 + 4 * SL, 1536),  // T1280..1792
       d, d, 1);

  // ---- reductions & outputs ----
  qgemm<<<dim3(8, 8, 2), 256, 0, stream>>>(WTh, UTh, UTl, Qpart);
  rgemm<<<dim3(7, 4), 512, 0, stream>>>(Pf1, Qpart, Rpart);
  sgemm<<<dim3(7, 4), 512, 0, stream>>>(Pf2, Qpart, Rpart, Spart);
  finalize_kernel<<<256, 64, 0, stream>>>(C, Qpart, Rpart, Spart, yh, out);

  // ---- u_t ----
  weights_kernel<<<306, 256, 0, stream>>>(ynh, sig, phi, lam, pt, wvec, out);
  ut_gemv<<<1024, 256, 0, stream>>>(M, Mb, wvec, out);
}

// Round 6
// 310.218 us; speedup vs baseline: 2.8910x; 1.0526x over previous
//
#include <hip/hip_runtime.h>

#define L_HIST 2048
typedef unsigned short ushortT;
typedef __attribute__((ext_vector_type(8))) short bf16x8;
typedef __attribute__((ext_vector_type(4))) short bf16x4;
typedef __attribute__((ext_vector_type(16))) float f32x16;

__device__ __forceinline__ ushortT f2bf(float x) {
  union { float f; unsigned u; } v; v.f = x;
  unsigned r = (v.u + 0x7FFFu + ((v.u >> 16) & 1u)) >> 16;
  return (ushortT)r;
}
__device__ __forceinline__ float bf2f(ushortT h) {
  union { unsigned u; float f; } v; v.u = ((unsigned)h) << 16; return v.f;
}
__device__ __forceinline__ bf16x4 lo4(bf16x8 v) {
  return __builtin_shufflevector(v, v, 0, 1, 2, 3);
}
__device__ __forceinline__ bf16x4 hi4(bf16x8 v) {
  return __builtin_shufflevector(v, v, 4, 5, 6, 7);
}
__device__ __forceinline__ bf16x8 rd8(const ushortT* p) {
  bf16x4 a = *(const bf16x4*)p, b = *(const bf16x4*)(p + 4);
  return __builtin_shufflevector(a, b, 0, 1, 2, 3, 4, 5, 6, 7);
}

// ---------------- job-table 2-product bf16 bt-GEMM --------------------------
// D[m][n] = sum_k Ph[m][k] * (Qh+Ql)[n][k];  K=512, ld=512.
// K-chunked 128 (4 sub-tiles of 32), single 54KB LDS buffer, 12-load prefetch.
struct Job {
  const ushortT *Ph, *Qh, *Ql;
  ushortT *Ch, *Cl;
  float *Cf;
  int M, tbase;
};
struct Prm { Job j[3]; int nj; };

__global__ __launch_bounds__(256) void bgemm(Prm p) {
  int bx = blockIdx.x;
  int ji = 0;
  if (p.nj > 1 && bx >= p.j[1].tbase) ji = 1;
  if (p.nj > 2 && bx >= p.j[2].tbase) ji = 2;
  Job J = p.j[ji];
  int lt = bx - J.tbase;
  int mt = J.M >> 6;
  int mtile = lt % mt, ntile = lt / mt;
  size_t m0 = (size_t)mtile * 64, n0 = (size_t)ntile * 64;

  __shared__ ushortT As[4][64][36];
  __shared__ ushortT Bhs[4][64][36];
  __shared__ ushortT Bls[4][64][36];

  int tid = threadIdx.x;
  int lane = tid & 63, wave = tid >> 6;
  int wm = (wave & 1) * 32, wn = (wave >> 1) * 32;
  int fr = lane & 31, fk = (lane >> 5) * 8;
  int row = tid >> 2, kp = (tid & 3) * 8;

  const ushortT* pA  = J.Ph + (m0 + row) * 512 + kp;
  const ushortT* pBh = J.Qh + (n0 + row) * 512 + kp;
  const ushortT* pBl = J.Ql + (n0 + row) * 512 + kp;

  bf16x8 rA[4], rBh[4], rBl[4];
#pragma unroll
  for (int s = 0; s < 4; ++s) {
    rA[s]  = *(const bf16x8*)(pA  + s * 32);
    rBh[s] = *(const bf16x8*)(pBh + s * 32);
    rBl[s] = *(const bf16x8*)(pBl + s * 32);
  }

  f32x16 acc;
#pragma unroll
  for (int i = 0; i < 16; ++i) acc[i] = 0.f;

  for (int c = 0; c < 4; ++c) {
#pragma unroll
    for (int s = 0; s < 4; ++s) {
      *(bf16x4*)&As[s][row][kp]      = lo4(rA[s]);
      *(bf16x4*)&As[s][row][kp + 4]  = hi4(rA[s]);
      *(bf16x4*)&Bhs[s][row][kp]     = lo4(rBh[s]);
      *(bf16x4*)&Bhs[s][row][kp + 4] = hi4(rBh[s]);
      *(bf16x4*)&Bls[s][row][kp]     = lo4(rBl[s]);
      *(bf16x4*)&Bls[s][row][kp + 4] = hi4(rBl[s]);
    }
    __syncthreads();
    if (c < 3) {
      int off = (c + 1) * 128;
#pragma unroll
      for (int s = 0; s < 4; ++s) {
        rA[s]  = *(const bf16x8*)(pA  + off + s * 32);
        rBh[s] = *(const bf16x8*)(pBh + off + s * 32);
        rBl[s] = *(const bf16x8*)(pBl + off + s * 32);
      }
    }
#pragma unroll
    for (int s = 0; s < 4; ++s)
#pragma unroll
      for (int ks = 0; ks < 32; ks += 16) {
        bf16x8 a  = rd8(&As[s][wm + fr][ks + fk]);
        bf16x8 bh = rd8(&Bhs[s][wn + fr][ks + fk]);
        bf16x8 bl = rd8(&Bls[s][wn + fr][ks + fk]);
        acc = __builtin_amdgcn_mfma_f32_32x32x16_bf16(a, bh, acc, 0, 0, 0);
        acc = __builtin_amdgcn_mfma_f32_32x32x16_bf16(a, bl, acc, 0, 0, 0);
      }
    __syncthreads();
  }
#pragma unroll
  for (int i = 0; i < 16; ++i) {
    int r = wm + (i & 3) + ((i >> 2) << 3) + ((lane >> 5) << 2);
    int c = wn + (lane & 31);
    float v = acc[i];
    size_t off = (m0 + r) * 512 + (n0 + c);
    ushortT h = f2bf(v);
    J.Ch[off] = h;
    if (J.Cl) J.Cl[off] = f2bf(v - bf2f(h));
    if (J.Cf) J.Cf[off] = v;
  }
}

// ---------------- Q = W * U via MFMA, K-chunked 128, transpose stage --------
// Qpart[z][m][j] = sum_{k in z-chunk(1024)} Wh[m][k]*(Uh+Ul)[k][j]
__global__ __launch_bounds__(256) void qgemm(
    const ushortT* __restrict__ WTh, const ushortT* __restrict__ UTh,
    const ushortT* __restrict__ UTl, float* __restrict__ Qpart) {
  int z = blockIdx.x, mtile = blockIdx.y, ntile = blockIdx.z;
  int m0 = mtile * 64, n0 = ntile * 64, k0 = z * 1024;

  __shared__ ushortT As[4][64][36];
  __shared__ ushortT Bhs[4][64][36];
  __shared__ ushortT Bls[4][64][36];

  int tid = threadIdx.x;
  int lane = tid & 63, wave = tid >> 6;
  int wm = (wave & 1) * 32, wn = (wave >> 1) * 32;
  int fr = lane & 31, fk = (lane >> 5) * 8;
  int ka = tid & 31, ma = (tid >> 5) * 8;
  int jb = tid >> 2, kb = (tid & 3) * 8;

  const ushortT* pW  = WTh + (size_t)(k0 + ka) * 512 + m0 + ma;
  const ushortT* pUh = UTh + (size_t)(n0 + jb) * 8192 + k0 + kb;
  const ushortT* pUl = UTl + (size_t)(n0 + jb) * 8192 + k0 + kb;

  bf16x8 rW[4], rUh[4], rUl[4];
#pragma unroll
  for (int s = 0; s < 4; ++s) {
    rW[s]  = *(const bf16x8*)(pW + (size_t)(s * 32) * 512);
    rUh[s] = *(const bf16x8*)(pUh + s * 32);
    rUl[s] = *(const bf16x8*)(pUl + s * 32);
  }

  f32x16 acc;
#pragma unroll
  for (int i = 0; i < 16; ++i) acc[i] = 0.f;

  for (int c = 0; c < 8; ++c) {
#pragma unroll
    for (int s = 0; s < 4; ++s) {
#pragma unroll
      for (int e = 0; e < 8; ++e) As[s][ma + e][ka] = (ushortT)rW[s][e];
      *(bf16x4*)&Bhs[s][jb][kb]     = lo4(rUh[s]);
      *(bf16x4*)&Bhs[s][jb][kb + 4] = hi4(rUh[s]);
      *(bf16x4*)&Bls[s][jb][kb]     = lo4(rUl[s]);
      *(bf16x4*)&Bls[s][jb][kb + 4] = hi4(rUl[s]);
    }
    __syncthreads();
    if (c < 7) {
      int off = (c + 1) * 128;
#pragma unroll
      for (int s = 0; s < 4; ++s) {
        rW[s]  = *(const bf16x8*)(pW + (size_t)(off + s * 32) * 512);
        rUh[s] = *(const bf16x8*)(pUh + off + s * 32);
        rUl[s] = *(const bf16x8*)(pUl + off + s * 32);
      }
    }
#pragma unroll
    for (int s = 0; s < 4; ++s)
#pragma unroll
      for (int ks = 0; ks < 32; ks += 16) {
        bf16x8 a  = rd8(&As[s][wm + fr][ks + fk]);
        bf16x8 bh = rd8(&Bhs[s][wn + fr][ks + fk]);
        bf16x8 bl = rd8(&Bls[s][wn + fr][ks + fk]);
        acc = __builtin_amdgcn_mfma_f32_32x32x16_bf16(a, bh, acc, 0, 0, 0);
        acc = __builtin_amdgcn_mfma_f32_32x32x16_bf16(a, bl, acc, 0, 0, 0);
      }
    __syncthreads();
  }
#pragma unroll
  for (int i = 0; i < 16; ++i) {
    int r = wm + (i & 3) + ((i >> 2) << 3) + ((lane >> 5) << 2);
    int c = wn + (lane & 31);
    Qpart[((size_t)z * 512 + m0 + r) * 128 + n0 + c] = acc[i];
  }
}

// ---------------- fused init: split A, split B(hi), pack U ------------------
__global__ void init_all(const float* __restrict__ A, const float* __restrict__ B,
                         const float* __restrict__ uh,
                         ushortT* N1h, ushortT* N1l, ushortT* T1h, ushortT* T1l,
                         ushortT* WTh, ushortT* UTh, ushortT* UTl) {
  int idx = blockIdx.x * 256 + threadIdx.x;
  if (idx < 262144) {
    int r = idx >> 9, c = idx & 511;
    float x = A[idx];
    ushortT h = f2bf(x); ushortT l = f2bf(x - bf2f(h));
    N1h[idx] = h; N1l[idx] = l;
    T1h[c * 512 + r] = h; T1l[c * 512 + r] = l;
  } else if (idx < 262144 + 131072) {
    int i2 = idx - 262144;
    int d = i2 >> 8, c = i2 & 255;
    WTh[c * 512 + d] = f2bf(B[i2]);
  } else {
    int i2 = idx - 393216;          // < 128*8192
    int j = i2 >> 13, k = i2 & 8191;
    int tau = k >> 8, c = k & 255;
    float v = 0.f;
    if (j < 64) v = uh[(size_t)(L_HIST - 1 - (32 * j + tau)) * 256 + c];
    else if (j == 64 && tau < 16) v = uh[(size_t)(L_HIST - 1 - tau) * 256 + c];
    ushortT h = f2bf(v);
    UTh[i2] = h; UTl[i2] = f2bf(v - bf2f(h));
  }
}

// ---------------- R partials (reads fp32 stacks + Qpart inline) -------------
__global__ __launch_bounds__(512) void rgemm(const float* __restrict__ Pf1,
                                             const float* __restrict__ Qpart,
                                             float* __restrict__ Rpart) {
  int j1 = blockIdx.x + 1;     // 1..7
  int dc = blockIdx.y;         // 0..3
  int d0 = dc * 128;
  int m = threadIdx.x;
  __shared__ float Qs[128][8];
  for (int i = threadIdx.x; i < 1024; i += 512) {
    int dd = i >> 3, jj = i & 7;
    float s = 0.f;
#pragma unroll
    for (int z = 0; z < 8; ++z)
      s += Qpart[((size_t)z * 512 + d0 + dd) * 128 + j1 + 8 * jj];
    Qs[dd][jj] = s;
  }
  __syncthreads();
  float acc[8];
#pragma unroll
  for (int jj = 0; jj < 8; ++jj) acc[jj] = 0.f;
  for (int d = 0; d < 128; ++d) {
    float tv = Pf1[((size_t)(j1 - 1) * 512 + d0 + d) * 512 + m];
    float4 q0 = *(const float4*)&Qs[d][0];
    float4 q1 = *(const float4*)&Qs[d][4];
    acc[0] += tv * q0.x; acc[1] += tv * q0.y; acc[2] += tv * q0.z; acc[3] += tv * q0.w;
    acc[4] += tv * q1.x; acc[5] += tv * q1.y; acc[6] += tv * q1.z; acc[7] += tv * q1.w;
  }
  float* dst = Rpart + (size_t)((j1 - 1) * 4 + dc) * 4096 + m * 8;
#pragma unroll
  for (int jj = 0; jj < 8; ++jj) dst[jj] = acc[jj];
}

// ---------------- S partials (assembles Rb rows inline) ---------------------
__global__ __launch_bounds__(512) void sgemm(const float* __restrict__ Pf2,
                                             const float* __restrict__ Qpart,
                                             const float* __restrict__ Rpart,
                                             float* __restrict__ Spart) {
  int j2 = blockIdx.x + 1;     // 1..7
  int dc = blockIdx.y;         // 0..3
  int d0 = dc * 128;
  int m = threadIdx.x;
  __shared__ float Rs[128];
  if (threadIdx.x < 128) {
    int dd = threadIdx.x;
    float s = 0.f;
#pragma unroll
    for (int z = 0; z < 8; ++z)
      s += Qpart[((size_t)z * 512 + d0 + dd) * 128 + 8 * j2];
    for (int p = 0; p < 28; ++p)
      s += Rpart[(size_t)p * 4096 + (d0 + dd) * 8 + j2];
    Rs[dd] = s;
  }
  __syncthreads();
  float acc = 0.f;
  for (int d = 0; d < 128; ++d)
    acc += Pf2[((size_t)(j2 - 1) * 512 + d0 + d) * 512 + m] * Rs[d];
  Spart[(size_t)((j2 - 1) * 4 + dc) * 512 + m] = acc;
}

// ---------------- finalize: y_nat & pred (assembles s inline) ---------------
__global__ __launch_bounds__(64) void finalize_kernel(
    const float* __restrict__ Cmat, const float* __restrict__ Qpart,
    const float* __restrict__ Rpart, const float* __restrict__ Spart,
    const float* __restrict__ yh, float* __restrict__ out) {
  int p = blockIdx.x;
  int lane = threadIdx.x;
  float a1 = 0.f, a2 = 0.f;
  for (int t = lane; t < 512; t += 64) {
    float sb = 0.f, qp = 0.f;
#pragma unroll
    for (int z = 0; z < 8; ++z) {
      sb += Qpart[((size_t)z * 512 + t) * 128 + 0];
      qp += Qpart[((size_t)z * 512 + t) * 128 + 64];
    }
    for (int q = 0; q < 28; ++q) {
      sb += Rpart[(size_t)q * 4096 + t * 8];
      sb += Spart[(size_t)q * 512 + t];
    }
    float cv = Cmat[(size_t)p * 512 + t];
    a1 += cv * sb;
    a2 += cv * qp;
  }
  for (int off = 32; off > 0; off >>= 1) {
    a1 += __shfl_down(a1, off);
    a2 += __shfl_down(a2, off);
  }
  if (lane == 0) {
    float ynat = yh[(size_t)(L_HIST - 1) * 256 + p] - a1;
    out[p] = ynat;
    out[256 + p] = ynat + a2;
  }
}

// ---------------- u_t weight vectors (verified R1-R5) -----------------------
__global__ __launch_bounds__(256) void weights_kernel(
    const float* __restrict__ ynh, const float* __restrict__ sigma,
    const float* __restrict__ phi, const float* __restrict__ lambda_e,
    const float* __restrict__ phi_tilde, float* __restrict__ wvec,
    float* __restrict__ out) {
  int v = blockIdx.x;
  int p = threadIdx.x;
  __shared__ float w4[48];
  float val = 0.f;
  if (v == 0) {
    val = ynh[(size_t)(L_HIST - 1) * 256 + p];
    out[512 + p] = 0.f;
  } else if (v <= 16) {
    int i = v - 1;
    float s = 0.f;
    for (int j = 0; j < 24; ++j)
      s += phi_tilde[j * 16 + i] * ynh[(size_t)(L_HIST - 2 - j) * 256 + p];
    val = powf(lambda_e[i], 0.25f) * s;
  } else if (v <= 33) {
    int l = v - 17;
    float s = 0.f;
    for (int k = 0; k < 25; ++k)
      s += phi[k * 17 + l] * ynh[(size_t)(L_HIST - 1 - k) * 256 + p];
    val = powf(sigma[l], 0.25f) * s;
  } else {
    int t = v - 34;
    int i = t / 17, l = t % 17;
    if (p < 48) {
      int m = p;
      int jlo = m - 24; if (jlo < 0) jlo = 0;
      int jhi = m; if (jhi > 23) jhi = 23;
      float s = 0.f;
      for (int j = jlo; j <= jhi; ++j)
        s += phi_tilde[j * 16 + i] * phi[(m - j) * 17 + l];
      w4[p] = s;
    }
    __syncthreads();
    float s = 0.f;
    for (int m = 0; m < 48; ++m)
      s += w4[m] * ynh[(size_t)(L_HIST - 3 - m) * 256 + p];
    val = powf(lambda_e[i], 0.25f) * powf(sigma[l], 0.25f) * s;
  }
  wvec[v * 256 + p] = val;
}

// ---------------- u_t: streaming matvec sum, 4-way v split ------------------
__global__ __launch_bounds__(256) void ut_gemv(
    const float* __restrict__ Mtens, const float* __restrict__ Mbar,
    const float* __restrict__ wvec, float* __restrict__ out) {
  int n = blockIdx.x & 255;
  int h = blockIdx.x >> 8;     // 0..3
  int lane = threadIdx.x & 63;
  int wid = threadIdx.x >> 6;
  int vs = (306 * h) >> 2, ve = (306 * (h + 1)) >> 2;
  float4 acc = {0.f, 0.f, 0.f, 0.f};
#pragma unroll 4
  for (int v = vs + wid; v < ve; v += 4) {
    const float* mat = (v < 17 ? Mbar : Mtens - 17 * 65536) + (size_t)v * 65536;
    float4 mv = ((const float4*)(mat + (size_t)n * 256))[lane];
    float4 wv = ((const float4*)(wvec + (size_t)v * 256))[lane];
    acc.x += mv.x * wv.x; acc.y += mv.y * wv.y;
    acc.z += mv.z * wv.z; acc.w += mv.w * wv.w;
  }
  float a = (acc.x + acc.y) + (acc.z + acc.w);
  for (int off = 32; off > 0; off >>= 1) a += __shfl_down(a, off);
  if (lane == 0) atomicAdd(&out[512 + n], a);
}

// ---------------- host orchestration ----------------------------------------
extern "C" void kernel_launch(void* const* d_in, const int* in_sizes, int n_in,
                              void* d_out, int out_size, void* d_ws, size_t ws_size,
                              hipStream_t stream) {
  (void)in_sizes; (void)n_in; (void)out_size; (void)ws_size;
  const float* A   = (const float*)d_in[0];
  const float* B   = (const float*)d_in[1];
  const float* C   = (const float*)d_in[2];
  const float* M   = (const float*)d_in[3];
  const float* Mb  = (const float*)d_in[4];
  const float* sig = (const float*)d_in[5];
  const float* phi = (const float*)d_in[6];
  const float* lam = (const float*)d_in[7];
  const float* pt  = (const float*)d_in[8];
  const float* yh  = (const float*)d_in[9];
  const float* uh  = (const float*)d_in[10];
  const float* ynh = (const float*)d_in[11];
  float* out = (float*)d_out;
  char* base = (char*)d_ws;

  const size_t MB = 1u << 20;
  const size_t SL = 512 * 512;            // elems per 512x512 plane
  ushortT* POW  = (ushortT*)base;                 // 16 slots x (hi+lo) = 16 MB
  ushortT* WTh  = (ushortT*)(base + 16 * MB);     // 8192x512 (8 MB)
  ushortT* P1th = (ushortT*)(base + 26 * MB);     // 7 x SL
  ushortT* P1tl = (ushortT*)(base + 30 * MB);
  ushortT* P2th = (ushortT*)(base + 34 * MB);
  ushortT* P2tl = (ushortT*)(base + 38 * MB);
  float*   Pf1  = (float*)(base + 42 * MB);       // 7 x SL fp32
  float*   Pf2  = (float*)(base + 50 * MB);
  ushortT* UTh  = (ushortT*)(base + 58 * MB);     // 128x8192 (2 MB)
  ushortT* UTl  = (ushortT*)(base + 60 * MB);
  float*   Qpart= (float*)(base + 62 * MB);       // 8x512x128 (2 MB)
  float*   Rpart= (float*)(base + 64 * MB);       // 28x4096
  float*   Spart= Rpart + 28 * 4096;              // 28x512
  float*   wvec = Spart + 28 * 512;               // 306x256

  auto ph = [&](int i) { return POW + (size_t)i * 2 * SL; };
  auto pl = [&](int i) { return POW + (size_t)i * 2 * SL + SL; };
  // slots: 0:N1 1:T1 2:N2 3:T2 4:N4 5:T4 6:N8 7:T8 8:N16 9:T16
  //        10:N32 11:N64 12:N128 13:N256 14:N512 15:N1024
  auto e1h = [&](int j) { return P1th + (size_t)(j - 1) * SL; };
  auto e1l = [&](int j) { return P1tl + (size_t)(j - 1) * SL; };
  auto e2h = [&](int j) { return P2th + (size_t)(j - 1) * SL; };
  auto e2l = [&](int j) { return P2tl + (size_t)(j - 1) * SL; };

  auto mkJ = [&](const ushortT* Ph, const ushortT* Qh, const ushortT* Ql,
                 ushortT* Ch, ushortT* Cl, float* Cf, int Mrows) {
    Job j; j.Ph = Ph; j.Qh = Qh; j.Ql = Ql;
    j.Ch = Ch; j.Cl = Cl; j.Cf = Cf; j.M = Mrows; j.tbase = 0; return j;
  };
  auto runL = [&](Job j0, Job j1, Job j2, int nj) {
    Prm p; p.j[0] = j0; p.j[1] = (nj > 1) ? j1 : j0; p.j[2] = (nj > 2) ? j2 : j0;
    p.nj = nj;
    int tb = 0;
    for (int i = 0; i < nj; ++i) { p.j[i].tbase = tb; tb += (p.j[i].M >> 6) * 8; }
    bgemm<<<tb, 256, 0, stream>>>(p);
  };

  // ---- init (one node) ----
  init_all<<<5632, 256, 0, stream>>>(A, B, uh, ph(0), pl(0), ph(1), pl(1),
                                     WTh, UTh, UTl);

  Job d = mkJ(ph(0), ph(1), pl(1), ph(2), pl(2), nullptr, 512); // dummy
  // ---- dual power/W/stack chain: 11 launches ----
  runL(mkJ(ph(0), ph(1), pl(1), ph(2), pl(2), nullptr, 512),              // N2
       mkJ(ph(1), ph(0), pl(0), ph(3), pl(3), nullptr, 512),              // T2
       mkJ(WTh, ph(0), pl(0), WTh + 256 * 512, nullptr, nullptr, 256), 3);// W1
  runL(mkJ(ph(2), ph(3), pl(3), ph(4), pl(4), nullptr, 512),              // N4
       mkJ(ph(3), ph(2), pl(2), ph(5), pl(5), nullptr, 512),              // T4
       mkJ(WTh, ph(2), pl(2), WTh + 512 * 512, nullptr, nullptr, 512), 3);// W2:4
  runL(mkJ(ph(4), ph(5), pl(5), ph(6), pl(6), nullptr, 512),              // N8
       mkJ(ph(5), ph(4), pl(4), ph(7), pl(7), nullptr, 512),              // T8
       mkJ(WTh, ph(4), pl(4), WTh + 1024 * 512, nullptr, nullptr, 1024), 3); // W4:8
  runL(mkJ(ph(6), ph(7), pl(7), ph(8), pl(8), nullptr, 512),              // N16
       mkJ(ph(7), ph(6), pl(6), ph(9), pl(9), nullptr, 512),              // T16
       mkJ(WTh, ph(6), pl(6), WTh + 2048 * 512, nullptr, nullptr, 2048), 3); // W8:16
  runL(mkJ(ph(8), ph(9), pl(9), ph(10), pl(10), nullptr, 512),            // N32
       mkJ(ph(9), ph(8), pl(8), e1h(1), e1l(1), Pf1, 512),                // T32
       mkJ(WTh, ph(8), pl(8), WTh + 4096 * 512, nullptr, nullptr, 4096), 3); // W16:32
  runL(mkJ(ph(10), e1h(1), e1l(1), ph(11), pl(11), nullptr, 512),         // N64
       mkJ(e1h(1), ph(10), pl(10), e1h(2), e1l(2), Pf1 + SL, 512),        // T64
       d, 2);
  runL(mkJ(ph(11), e1h(2), e1l(2), ph(12), pl(12), nullptr, 512),         // N128
       mkJ(e1h(1), ph(11), pl(11), e1h(3), e1l(3), Pf1 + 2 * SL, 1024),   // T96,T128
       d, 2);
  runL(mkJ(ph(12), e1h(4), e1l(4), ph(13), pl(13), nullptr, 512),         // N256
       mkJ(e1h(1), ph(12), pl(12), e1h(5), nullptr, Pf1 + 4 * SL, 1536),  // T160..224
       mkJ(e1h(4), ph(12), pl(12), e2h(1), e2l(1), Pf2, 512), 3);         // T256
  runL(mkJ(ph(13), e2h(1), e2l(1), ph(14), pl(14), nullptr, 512),         // N512
       mkJ(e2h(1), ph(13), pl(13), e2h(2), e2l(2), Pf2 + SL, 512),        // T512
       d, 2);
  runL(mkJ(ph(14), e2h(2), e2l(2), ph(15), pl(15), nullptr, 512),         // N1024
       mkJ(e2h(1), ph(14), pl(14), e2h(3), nullptr, Pf2 + 2 * SL, 1024),  // T768,T1024
       d, 2);
  runL(mkJ(e2h(1), ph(15), pl(15), e2h(5), nullptr, Pf2 + 4 * SL, 1536),  // T1280..1792
       d, d, 1);

  // ---- reductions & outputs ----
  qgemm<<<dim3(8, 8, 2), 256, 0, stream>>>(WTh, UTh, UTl, Qpart);
  rgemm<<<dim3(7, 4), 512, 0, stream>>>(Pf1, Qpart, Rpart);
  sgemm<<<dim3(7, 4), 512, 0, stream>>>(Pf2, Qpart, Rpart, Spart);
  finalize_kernel<<<256, 64, 0, stream>>>(C, Qpart, Rpart, Spart, yh, out);

  // ---- u_t ----
  weights_kernel<<<306, 256, 0, stream>>>(ynh, sig, phi, lam, pt, wvec, out);
  ut_gemv<<<1024, 256, 0, stream>>>(M, Mb, wvec, out);
}